// Round 1
// baseline (471.955 us; speedup 1.0000x reference)
//
#include <hip/hip_runtime.h>
#include <stdint.h>

#pragma clang fp contract(off)

#define NB 16
#define NC 80
#define P_TOT 17064
#define PRE_K 1000
#define POST_K 100

__device__ __forceinline__ float sigmoidf_(float x) {
  return 1.0f / (1.0f + expf(-x));
}

__global__ __launch_bounds__(256) void decode_kernel(
    const float* __restrict__ cls0, const float* __restrict__ reg0, const float* __restrict__ ctr0,
    const float* __restrict__ cls1, const float* __restrict__ reg1, const float* __restrict__ ctr1,
    const float* __restrict__ cls2, const float* __restrict__ reg2, const float* __restrict__ ctr2,
    const float* __restrict__ cls3, const float* __restrict__ reg3, const float* __restrict__ ctr3,
    const float* __restrict__ cls4, const float* __restrict__ reg4, const float* __restrict__ ctr4,
    float* __restrict__ scores, int* __restrict__ labels, float* __restrict__ boxes,
    unsigned long long* __restrict__ keys)
{
  int p = blockIdx.x * blockDim.x + threadIdx.x;
  int n = blockIdx.y;
  if (p >= P_TOT) return;
  int off, wsh, hw; float stride; const float *cls, *reg, *ctr;
  if (p < 12800)      { off = 0;     wsh = 7; hw = 12800; stride = 8.f;   cls = cls0; reg = reg0; ctr = ctr0; }
  else if (p < 16000) { off = 12800; wsh = 6; hw = 3200;  stride = 16.f;  cls = cls1; reg = reg1; ctr = ctr1; }
  else if (p < 16800) { off = 16000; wsh = 5; hw = 800;   stride = 32.f;  cls = cls2; reg = reg2; ctr = ctr2; }
  else if (p < 17008) { off = 16800; wsh = 4; hw = 208;   stride = 64.f;  cls = cls3; reg = reg3; ctr = ctr3; }
  else                { off = 17008; wsh = 3; hw = 56;    stride = 128.f; cls = cls4; reg = reg4; ctr = ctr4; }
  int loc = p - off;
  int y = loc >> wsh;
  int x = loc & ((1 << wsh) - 1);

  float sctr = sigmoidf_(ctr[(size_t)n * hw + loc]);
  const float* cbase = cls + (size_t)n * NC * hw + loc;
  float best = -1.f; int bl = 0;
  for (int c = 0; c < NC; ++c) {
    float v = sqrtf(sigmoidf_(cbase[(size_t)c * hw]) * sctr);
    if (v > best) { best = v; bl = c; }
  }
  float val = (best > 0.05f) ? best : 0.0f;

  const float* rbase = reg + (size_t)n * 4 * hw + loc;
  float dl = rbase[0], dt = rbase[(size_t)hw], dr = rbase[(size_t)2*hw], db = rbase[(size_t)3*hw];
  float px = (float)x * stride + 0.5f * stride;
  float py = (float)y * stride + 0.5f * stride;
  float x1 = fminf(fmaxf(px - dl, 0.f), 1024.f);
  float y1 = fminf(fmaxf(py - dt, 0.f), 800.f);
  float x2 = fminf(fmaxf(px + dr, 0.f), 1024.f);
  float y2 = fminf(fmaxf(py + db, 0.f), 800.f);

  size_t o = (size_t)n * P_TOT + p;
  scores[o] = val;
  labels[o] = bl;
  boxes[4*o+0] = x1; boxes[4*o+1] = y1; boxes[4*o+2] = x2; boxes[4*o+3] = y2;
  keys[o] = ((unsigned long long)__float_as_uint(val) << 32)
          | (unsigned long long)(0xFFFFFFFFu - (unsigned)p);
}

// One block per batch: exact top-1000 (desc by key) via MSB radix select + bitonic sort.
__global__ __launch_bounds__(1024) void topk_kernel(
    const unsigned long long* __restrict__ keys, unsigned long long* __restrict__ topkeys)
{
  int n = blockIdx.x;
  int tid = threadIdx.x;
  __shared__ unsigned hist[256];
  __shared__ unsigned long long s_kth;
  __shared__ unsigned s_K;
  __shared__ unsigned s_cnt;
  __shared__ unsigned long long skey[1024];
  const unsigned long long* bk = keys + (size_t)n * P_TOT;

  if (tid == 0) { s_K = PRE_K; s_kth = 0ULL; }
  for (int pass = 0; pass < 8; ++pass) {
    int shift = 56 - 8 * pass;
    if (tid < 256) hist[tid] = 0;
    __syncthreads();
    unsigned long long pfx = s_kth;
    unsigned long long mask = (pass == 0) ? 0ULL : (~0ULL << (64 - 8 * pass));
    for (int p = tid; p < P_TOT; p += 1024) {
      unsigned long long k = bk[p];
      if ((k & mask) == pfx)
        atomicAdd(&hist[(unsigned)(k >> shift) & 255u], 1u);
    }
    __syncthreads();
    if (tid == 0) {
      unsigned K = s_K, cum = 0;
      int d;
      for (d = 255; d >= 0; --d) {
        unsigned c = hist[d];
        if (cum + c >= K) break;
        cum += c;
      }
      if (d < 0) d = 0;
      s_K = K - cum;
      s_kth = pfx | ((unsigned long long)(unsigned)d << shift);
    }
    __syncthreads();
  }
  unsigned long long kth = s_kth;
  skey[tid] = 0ULL;
  if (tid == 0) s_cnt = 0;
  __syncthreads();
  for (int p = tid; p < P_TOT; p += 1024) {
    unsigned long long k = bk[p];
    if (k >= kth) {
      unsigned pos = atomicAdd(&s_cnt, 1u);
      if (pos < 1024) skey[pos] = k;
    }
  }
  __syncthreads();
  // bitonic sort, descending
  for (int k2 = 2; k2 <= 1024; k2 <<= 1) {
    for (int j = k2 >> 1; j > 0; j >>= 1) {
      int ixj = tid ^ j;
      if (ixj > tid) {
        unsigned long long a = skey[tid], b = skey[ixj];
        bool sw = ((tid & k2) == 0) ? (a < b) : (a > b);
        if (sw) { skey[tid] = b; skey[ixj] = a; }
      }
      __syncthreads();
    }
  }
  topkeys[(size_t)n * 1024 + tid] = skey[tid];
}

__global__ __launch_bounds__(256) void gather_kernel(
    const unsigned long long* __restrict__ topkeys,
    const float* __restrict__ boxes, const int* __restrict__ labels,
    float* __restrict__ tboxes, float* __restrict__ tscores, int* __restrict__ tlabels)
{
  int i = blockIdx.x * 256 + threadIdx.x;
  if (i >= NB * PRE_K) return;
  int n = i / PRE_K;
  int r = i - n * PRE_K;
  unsigned long long k = topkeys[(size_t)n * 1024 + r];
  unsigned idx = 0xFFFFFFFFu - (unsigned)(k & 0xFFFFFFFFu);
  float sc = __uint_as_float((unsigned)(k >> 32));
  size_t src = (size_t)n * P_TOT + idx;
  tscores[i] = sc;
  tlabels[i] = labels[src];
  tboxes[4*(size_t)i+0] = boxes[4*src+0];
  tboxes[4*(size_t)i+1] = boxes[4*src+1];
  tboxes[4*(size_t)i+2] = boxes[4*src+2];
  tboxes[4*(size_t)i+3] = boxes[4*src+3];
}

// Suppression bitmask rows: supp[n][i][w] bit b set iff j=w*64+b > i, same label,
// IoU(offset boxes) > 0.6.  Offset boxes replicate the reference's f32 rounding.
__global__ __launch_bounds__(128) void iou_kernel(
    const float* __restrict__ tboxes, const int* __restrict__ tlabels,
    unsigned long long* __restrict__ supp)
{
  __shared__ float4 sb[PRE_K];
  __shared__ int slb[PRE_K];
  int n = blockIdx.y;
  for (int j = threadIdx.x; j < PRE_K; j += 128) {
    const float* b = tboxes + ((size_t)n * PRE_K + j) * 4;
    int lb = tlabels[(size_t)n * PRE_K + j];
    float offv = (float)lb * 4096.0f;
    sb[j] = make_float4(b[0] + offv, b[1] + offv, b[2] + offv, b[3] + offv);
    slb[j] = lb;
  }
  __syncthreads();
  int i = blockIdx.x * 128 + threadIdx.x;
  if (i >= PRE_K) return;
  float4 bi = sb[i];
  int li = slb[i];
  float ai = (bi.z - bi.x) * (bi.w - bi.y);
  unsigned long long* orow = supp + ((size_t)n * PRE_K + i) * 16;
  for (int w = 0; w < 16; ++w) {
    unsigned long long m = 0;
    int jbase = w * 64;
    for (int b = 0; b < 64; ++b) {
      int j = jbase + b;
      if (j <= i || j >= PRE_K) continue;
      if (slb[j] != li) continue;
      float4 bj = sb[j];
      float aj = (bj.z - bj.x) * (bj.w - bj.y);
      float lx = fmaxf(bi.x, bj.x), ly = fmaxf(bi.y, bj.y);
      float rx = fminf(bi.z, bj.z), ry = fminf(bi.w, bj.w);
      float iw = fmaxf(rx - lx, 0.f), ih = fmaxf(ry - ly, 0.f);
      float inter = iw * ih;
      float iou = inter / (ai + aj - inter + 1e-9f);
      if (iou > 0.6f) m |= (1ull << b);
    }
    orow[w] = m;
  }
}

// One wave per batch: sequential greedy, removed mask distributed over lanes 0..15.
__global__ __launch_bounds__(64) void greedy_kernel(
    const unsigned long long* __restrict__ supp, const float* __restrict__ tscores,
    unsigned long long* __restrict__ keepmask)
{
  int n = blockIdx.x;
  int lane = threadIdx.x;
  __shared__ float ssc[PRE_K];
  for (int i = lane; i < PRE_K; i += 64) ssc[i] = tscores[(size_t)n * PRE_K + i];
  __syncthreads();
  const unsigned long long* S = supp + (size_t)n * PRE_K * 16;
  unsigned long long removed = 0;
  bool ld = (lane < 16);
  unsigned long long p0,p1,p2,p3,p4,p5,p6,p7;
  p0 = ld ? S[(size_t)0*16 + lane] : 0;
  p1 = ld ? S[(size_t)1*16 + lane] : 0;
  p2 = ld ? S[(size_t)2*16 + lane] : 0;
  p3 = ld ? S[(size_t)3*16 + lane] : 0;
  p4 = ld ? S[(size_t)4*16 + lane] : 0;
  p5 = ld ? S[(size_t)5*16 + lane] : 0;
  p6 = ld ? S[(size_t)6*16 + lane] : 0;
  p7 = ld ? S[(size_t)7*16 + lane] : 0;
  for (int i = 0; i < PRE_K; ++i) {
    unsigned long long row = p0;
    p0 = p1; p1 = p2; p2 = p3; p3 = p4; p4 = p5; p5 = p6; p6 = p7;
    p7 = (ld && (i + 8) < PRE_K) ? S[(size_t)(i + 8) * 16 + lane] : 0;
    int w = i >> 6;
    unsigned long long rw = __shfl(removed, w);
    bool rem = (rw >> (i & 63)) & 1ull;
    if (!rem && ssc[i] > 0.f) removed |= row;
  }
  if (lane < 16) keepmask[(size_t)n * 16 + lane] = removed;
}

__global__ __launch_bounds__(1024) void finalize_kernel(
    const unsigned long long* __restrict__ keepmask, const float* __restrict__ tscores,
    const float* __restrict__ tboxes, const int* __restrict__ tlabels,
    float* __restrict__ out)
{
  int n = blockIdx.x;
  int tid = threadIdx.x;
  __shared__ unsigned sk[1024];
  __shared__ unsigned sz[1024];
  bool inr = (tid < PRE_K);
  bool keep = false; float sc = 0.f;
  if (inr) {
    unsigned long long w = keepmask[(size_t)n * 16 + (tid >> 6)];
    bool rem = (w >> (tid & 63)) & 1ull;
    sc = tscores[(size_t)n * PRE_K + tid];
    keep = (!rem) && (sc > 0.f);
  }
  sk[tid] = keep ? 1u : 0u;
  sz[tid] = (inr && !keep) ? 1u : 0u;
  __syncthreads();
  for (int ofs = 1; ofs < 1024; ofs <<= 1) {
    unsigned a = (tid >= ofs) ? sk[tid - ofs] : 0;
    unsigned b = (tid >= ofs) ? sz[tid - ofs] : 0;
    __syncthreads();
    sk[tid] += a; sz[tid] += b;
    __syncthreads();
  }
  int nk = (int)sk[1023];
  int slot = -1;
  if (inr) {
    if (keep) {
      int r = (int)sk[tid] - 1;
      if (r < POST_K) slot = r;
    } else {
      int r = nk + (int)sz[tid] - 1;
      if (r < POST_K) slot = r;
    }
  }
  if (slot >= 0) {
    size_t src = (size_t)n * PRE_K + tid;
    size_t ob = ((size_t)n * POST_K + slot) * 4;
    out[ob+0] = tboxes[4*src+0];
    out[ob+1] = tboxes[4*src+1];
    out[ob+2] = tboxes[4*src+2];
    out[ob+3] = tboxes[4*src+3];
    out[(size_t)NB*POST_K*4 + (size_t)n*POST_K + slot] = keep ? sc : 0.0f;
    out[(size_t)NB*POST_K*5 + (size_t)n*POST_K + slot] = (float)tlabels[src];
  }
}

extern "C" void kernel_launch(void* const* d_in, const int* in_sizes, int n_in,
                              void* d_out, int out_size, void* d_ws, size_t ws_size,
                              hipStream_t stream) {
  char* w = (char*)d_ws;
  auto carve = [&](size_t bytes) { char* p = w; w += (bytes + 255) & ~(size_t)255; return p; };
  float* scores = (float*)carve((size_t)NB * P_TOT * 4);
  int* labels   = (int*)carve((size_t)NB * P_TOT * 4);
  float* boxes  = (float*)carve((size_t)NB * P_TOT * 16);
  unsigned long long* keys    = (unsigned long long*)carve((size_t)NB * P_TOT * 8);
  unsigned long long* topkeys = (unsigned long long*)carve((size_t)NB * 1024 * 8);
  float* tboxes  = (float*)carve((size_t)NB * PRE_K * 16);
  float* tscores = (float*)carve((size_t)NB * PRE_K * 4);
  int* tlabels   = (int*)carve((size_t)NB * PRE_K * 4);
  unsigned long long* supp     = (unsigned long long*)carve((size_t)NB * PRE_K * 16 * 8);
  unsigned long long* keepmask = (unsigned long long*)carve((size_t)NB * 16 * 8);

  const float* cls0 = (const float*)d_in[0];
  const float* reg0 = (const float*)d_in[1];
  const float* ctr0 = (const float*)d_in[2];
  const float* cls1 = (const float*)d_in[3];
  const float* reg1 = (const float*)d_in[4];
  const float* ctr1 = (const float*)d_in[5];
  const float* cls2 = (const float*)d_in[6];
  const float* reg2 = (const float*)d_in[7];
  const float* ctr2 = (const float*)d_in[8];
  const float* cls3 = (const float*)d_in[9];
  const float* reg3 = (const float*)d_in[10];
  const float* ctr3 = (const float*)d_in[11];
  const float* cls4 = (const float*)d_in[12];
  const float* reg4 = (const float*)d_in[13];
  const float* ctr4 = (const float*)d_in[14];

  dim3 dg((P_TOT + 255) / 256, NB);
  decode_kernel<<<dg, 256, 0, stream>>>(cls0, reg0, ctr0, cls1, reg1, ctr1,
                                        cls2, reg2, ctr2, cls3, reg3, ctr3,
                                        cls4, reg4, ctr4,
                                        scores, labels, boxes, keys);
  topk_kernel<<<NB, 1024, 0, stream>>>(keys, topkeys);
  gather_kernel<<<(NB * PRE_K + 255) / 256, 256, 0, stream>>>(topkeys, boxes, labels,
                                                              tboxes, tscores, tlabels);
  dim3 gi((PRE_K + 127) / 128, NB);
  iou_kernel<<<gi, 128, 0, stream>>>(tboxes, tlabels, supp);
  greedy_kernel<<<NB, 64, 0, stream>>>(supp, tscores, keepmask);
  finalize_kernel<<<NB, 1024, 0, stream>>>(keepmask, tscores, tboxes, tlabels, (float*)d_out);
}

// Round 2
// 369.738 us; speedup vs baseline: 1.2765x; 1.2765x over previous
//
#include <hip/hip_runtime.h>
#include <stdint.h>

#pragma clang fp contract(off)

#define NB 16
#define NC 80
#define P_TOT 17064
#define P4 (P_TOT / 4)
#define PRE_K 1000
#define POST_K 100

__device__ __forceinline__ float sigmoidf_(float x) {
  return 1.0f / (1.0f + expf(-x));
}

// 4 locations per thread, float4 loads. 4-packs never straddle a level or a row.
__global__ __launch_bounds__(256) void decode_kernel(
    const float* __restrict__ cls0, const float* __restrict__ reg0, const float* __restrict__ ctr0,
    const float* __restrict__ cls1, const float* __restrict__ reg1, const float* __restrict__ ctr1,
    const float* __restrict__ cls2, const float* __restrict__ reg2, const float* __restrict__ ctr2,
    const float* __restrict__ cls3, const float* __restrict__ reg3, const float* __restrict__ ctr3,
    const float* __restrict__ cls4, const float* __restrict__ reg4, const float* __restrict__ ctr4,
    float* __restrict__ scores, int* __restrict__ labels, float* __restrict__ boxes,
    unsigned long long* __restrict__ keys)
{
  int t = blockIdx.x * blockDim.x + threadIdx.x;
  int n = blockIdx.y;
  if (t >= P4) return;
  int p0 = t * 4;
  int off, wsh, hw; float stride; const float *cls, *reg, *ctr;
  if (p0 < 12800)      { off = 0;     wsh = 7; hw = 12800; stride = 8.f;   cls = cls0; reg = reg0; ctr = ctr0; }
  else if (p0 < 16000) { off = 12800; wsh = 6; hw = 3200;  stride = 16.f;  cls = cls1; reg = reg1; ctr = ctr1; }
  else if (p0 < 16800) { off = 16000; wsh = 5; hw = 800;   stride = 32.f;  cls = cls2; reg = reg2; ctr = ctr2; }
  else if (p0 < 17008) { off = 16800; wsh = 4; hw = 208;   stride = 64.f;  cls = cls3; reg = reg3; ctr = ctr3; }
  else                 { off = 17008; wsh = 3; hw = 56;    stride = 128.f; cls = cls4; reg = reg4; ctr = ctr4; }
  int loc0 = p0 - off;
  int y = loc0 >> wsh;
  int x0 = loc0 & ((1 << wsh) - 1);
  float py = (float)y * stride + 0.5f * stride;

  float4 c4 = *reinterpret_cast<const float4*>(ctr + (size_t)n * hw + loc0);
  float sctr[4] = { sigmoidf_(c4.x), sigmoidf_(c4.y), sigmoidf_(c4.z), sigmoidf_(c4.w) };

  const float* cbase = cls + (size_t)n * NC * hw + loc0;
  float best[4] = { -1.f, -1.f, -1.f, -1.f };
  int bl[4] = { 0, 0, 0, 0 };
  for (int c = 0; c < NC; ++c) {
    float4 cv = *reinterpret_cast<const float4*>(cbase + (size_t)c * hw);
    float v;
    v = sqrtf(sigmoidf_(cv.x) * sctr[0]); if (v > best[0]) { best[0] = v; bl[0] = c; }
    v = sqrtf(sigmoidf_(cv.y) * sctr[1]); if (v > best[1]) { best[1] = v; bl[1] = c; }
    v = sqrtf(sigmoidf_(cv.z) * sctr[2]); if (v > best[2]) { best[2] = v; bl[2] = c; }
    v = sqrtf(sigmoidf_(cv.w) * sctr[3]); if (v > best[3]) { best[3] = v; bl[3] = c; }
  }

  const float* rbase = reg + (size_t)n * 4 * hw + loc0;
  float4 rl = *reinterpret_cast<const float4*>(rbase);
  float4 rt = *reinterpret_cast<const float4*>(rbase + (size_t)hw);
  float4 rr = *reinterpret_cast<const float4*>(rbase + (size_t)2 * hw);
  float4 rb = *reinterpret_cast<const float4*>(rbase + (size_t)3 * hw);
  float dl[4] = { rl.x, rl.y, rl.z, rl.w };
  float dt[4] = { rt.x, rt.y, rt.z, rt.w };
  float dr[4] = { rr.x, rr.y, rr.z, rr.w };
  float db[4] = { rb.x, rb.y, rb.z, rb.w };

  size_t o0 = (size_t)n * P_TOT + p0;
  float4 val4; float* valp = &val4.x;
  int4 bl4; int* blp = &bl4.x;
  unsigned long long kk[4];
  #pragma unroll
  for (int e = 0; e < 4; ++e) {
    float px = (float)(x0 + e) * stride + 0.5f * stride;
    float val = (best[e] > 0.05f) ? best[e] : 0.0f;
    float x1 = fminf(fmaxf(px - dl[e], 0.f), 1024.f);
    float y1 = fminf(fmaxf(py - dt[e], 0.f), 800.f);
    float x2 = fminf(fmaxf(px + dr[e], 0.f), 1024.f);
    float y2 = fminf(fmaxf(py + db[e], 0.f), 800.f);
    valp[e] = val;
    blp[e] = bl[e];
    *reinterpret_cast<float4*>(boxes + 4 * (o0 + e)) = make_float4(x1, y1, x2, y2);
    kk[e] = ((unsigned long long)__float_as_uint(val) << 32)
          | (unsigned long long)(0xFFFFFFFFu - (unsigned)(p0 + e));
  }
  *reinterpret_cast<float4*>(scores + o0) = val4;
  *reinterpret_cast<int4*>(labels + o0) = bl4;
  ulonglong2 k01; k01.x = kk[0]; k01.y = kk[1];
  ulonglong2 k23; k23.x = kk[2]; k23.y = kk[3];
  *reinterpret_cast<ulonglong2*>(keys + o0) = k01;
  *reinterpret_cast<ulonglong2*>(keys + o0 + 2) = k23;
}

// One block per batch: exact top-1000 (desc by key) via MSB radix select + bitonic sort.
// Per-wave histograms (pitch 257 breaks bank aliasing) + parallel suffix-scan digit pick.
__global__ __launch_bounds__(1024) void topk_kernel(
    const unsigned long long* __restrict__ keys, unsigned long long* __restrict__ topkeys)
{
  int n = blockIdx.x;
  int tid = threadIdx.x;
  int wave = tid >> 6;
  int lane = tid & 63;
  __shared__ unsigned histW[16 * 257];
  __shared__ unsigned hist[256];
  __shared__ unsigned s_digit, s_Knext, s_cnt;
  __shared__ unsigned long long skey[1024];
  const unsigned long long* bk = keys + (size_t)n * P_TOT;

  unsigned long long pfx = 0ULL;
  unsigned K = PRE_K;
  for (int pass = 0; pass < 8; ++pass) {
    int shift = 56 - 8 * pass;
    unsigned long long mask = (pass == 0) ? 0ULL : (~0ULL << (64 - 8 * pass));
    for (int d = tid; d < 16 * 257; d += 1024) histW[d] = 0;
    __syncthreads();
    for (int p = tid; p < P_TOT; p += 1024) {
      unsigned long long k = bk[p];
      if ((k & mask) == pfx)
        atomicAdd(&histW[wave * 257 + ((unsigned)(k >> shift) & 255u)], 1u);
    }
    __syncthreads();
    if (tid < 256) {
      unsigned s = 0;
      for (int w2 = 0; w2 < 16; ++w2) s += histW[w2 * 257 + tid];
      hist[tid] = s;
    }
    __syncthreads();
    // suffix inclusive sum: hist[d] = sum_{d'>=d}
    for (int ofs = 1; ofs < 256; ofs <<= 1) {
      unsigned v = 0;
      if (tid < 256) { v = hist[tid]; if (tid + ofs < 256) v += hist[tid + ofs]; }
      __syncthreads();
      if (tid < 256) hist[tid] = v;
      __syncthreads();
    }
    if (tid < 256) {
      unsigned S = hist[tid];
      unsigned Snext = (tid < 255) ? hist[tid + 1] : 0u;
      if (S >= K && Snext < K) { s_digit = (unsigned)tid; s_Knext = K - Snext; }
    }
    __syncthreads();
    pfx |= ((unsigned long long)s_digit << shift);
    K = s_Knext;
    __syncthreads();
  }
  unsigned long long kth = pfx;
  skey[tid] = 0ULL;
  if (tid == 0) s_cnt = 0;
  __syncthreads();
  for (int p = tid; p < P_TOT; p += 1024) {
    unsigned long long k = bk[p];
    bool take = (k >= kth);
    unsigned long long b = __ballot(take);
    if (b) {
      int leader = __ffsll((unsigned long long)b) - 1;
      unsigned base = 0;
      if (lane == leader) base = atomicAdd(&s_cnt, (unsigned)__popcll(b));
      base = (unsigned)__shfl((int)base, leader);
      if (take) {
        unsigned pos = base + (unsigned)__popcll(b & ((1ull << lane) - 1ull));
        if (pos < 1024) skey[pos] = k;
      }
    }
  }
  __syncthreads();
  // bitonic sort, descending
  for (int k2 = 2; k2 <= 1024; k2 <<= 1) {
    for (int j = k2 >> 1; j > 0; j >>= 1) {
      int ixj = tid ^ j;
      if (ixj > tid) {
        unsigned long long a = skey[tid], b = skey[ixj];
        bool sw = ((tid & k2) == 0) ? (a < b) : (a > b);
        if (sw) { skey[tid] = b; skey[ixj] = a; }
      }
      __syncthreads();
    }
  }
  topkeys[(size_t)n * 1024 + tid] = skey[tid];
}

__global__ __launch_bounds__(256) void gather_kernel(
    const unsigned long long* __restrict__ topkeys,
    const float* __restrict__ boxes, const int* __restrict__ labels,
    float* __restrict__ tboxes, float* __restrict__ tscores, int* __restrict__ tlabels)
{
  int i = blockIdx.x * 256 + threadIdx.x;
  if (i >= NB * PRE_K) return;
  int n = i / PRE_K;
  int r = i - n * PRE_K;
  unsigned long long k = topkeys[(size_t)n * 1024 + r];
  unsigned idx = 0xFFFFFFFFu - (unsigned)(k & 0xFFFFFFFFu);
  float sc = __uint_as_float((unsigned)(k >> 32));
  size_t src = (size_t)n * P_TOT + idx;
  tscores[i] = sc;
  tlabels[i] = labels[src];
  tboxes[4*(size_t)i+0] = boxes[4*src+0];
  tboxes[4*(size_t)i+1] = boxes[4*src+1];
  tboxes[4*(size_t)i+2] = boxes[4*src+2];
  tboxes[4*(size_t)i+3] = boxes[4*src+3];
}

// COLUMN-major suppression: colsupp[n][j][w] bit b set iff row i=w*64+b < j,
// same label, IoU(offset boxes) > 0.6. (Offset replicates reference f32 rounding.)
__global__ __launch_bounds__(128) void iou_kernel(
    const float* __restrict__ tboxes, const int* __restrict__ tlabels,
    unsigned long long* __restrict__ colsupp)
{
  __shared__ float4 sb[PRE_K];
  __shared__ int slb[PRE_K];
  int n = blockIdx.y;
  for (int i = threadIdx.x; i < PRE_K; i += 128) {
    const float* b = tboxes + ((size_t)n * PRE_K + i) * 4;
    int lb = tlabels[(size_t)n * PRE_K + i];
    float offv = (float)lb * 4096.0f;
    sb[i] = make_float4(b[0] + offv, b[1] + offv, b[2] + offv, b[3] + offv);
    slb[i] = lb;
  }
  __syncthreads();
  int j = blockIdx.x * 128 + threadIdx.x;
  if (j >= PRE_K) return;
  float4 bj = sb[j];
  int lj = slb[j];
  float aj = (bj.z - bj.x) * (bj.w - bj.y);
  int wmax = j >> 6;
  unsigned long long* ocol = colsupp + ((size_t)n * PRE_K + j) * 16;
  for (int w = 0; w < 16; ++w) {
    unsigned long long m = 0;
    if (w <= wmax) {
      int ibase = w * 64;
      for (int b = 0; b < 64; ++b) {
        int i = ibase + b;
        if (i >= j) break;
        if (slb[i] != lj) continue;
        float4 bi = sb[i];
        float ai = (bi.z - bi.x) * (bi.w - bi.y);
        float lx = fmaxf(bi.x, bj.x), ly = fmaxf(bi.y, bj.y);
        float rx = fminf(bi.z, bj.z), ry = fminf(bi.w, bj.w);
        float iw = fmaxf(rx - lx, 0.f), ih = fmaxf(ry - ly, 0.f);
        float inter = iw * ih;
        float iou = inter / (ai + aj - inter + 1e-9f);
        if (iou > 0.6f) m |= (1ull << b);
      }
    }
    ocol[w] = m;
  }
}

// One wave per batch. Column-distributed removed state; within-chunk recurrence
// uses __ballot (register/SALU critical path, no shfl/LDS/global on the chain).
__global__ __launch_bounds__(64) void greedy_kernel(
    const unsigned long long* __restrict__ colsupp, const float* __restrict__ tscores,
    unsigned long long* __restrict__ keepmask)
{
  int n = blockIdx.x;
  int l = threadIdx.x;
  const unsigned long long* C = colsupp + (size_t)n * PRE_K * 16;
  const float* sc = tscores + (size_t)n * PRE_K;
  unsigned removedbits = 0;  // bit k: column index k*64+l removed

  for (int c = 0; c < 16; ++c) {
    int j = c * 64 + l;
    bool valid = (j < PRE_K);
    float s_l = valid ? sc[j] : 0.f;
    unsigned long long col_l = valid ? C[(size_t)j * 16 + c] : 0ULL;
    // cross-chunk words: static 16-unroll so all loads pipeline (no scratch)
    unsigned long long cw0, cw1, cw2, cw3, cw4, cw5, cw6, cw7;
    unsigned long long cw8, cw9, cw10, cw11, cw12, cw13, cw14, cw15;
    {
      #define LDW(K_) ((K_ * 64 + l) < PRE_K ? C[(size_t)(K_ * 64 + l) * 16 + c] : 0ULL)
      cw0 = LDW(0);  cw1 = LDW(1);  cw2 = LDW(2);  cw3 = LDW(3);
      cw4 = LDW(4);  cw5 = LDW(5);  cw6 = LDW(6);  cw7 = LDW(7);
      cw8 = LDW(8);  cw9 = LDW(9);  cw10 = LDW(10); cw11 = LDW(11);
      cw12 = LDW(12); cw13 = LDW(13); cw14 = LDW(14); cw15 = LDW(15);
      #undef LDW
    }
    unsigned long long sp = __ballot(s_l > 0.f);
    unsigned rem_l = (removedbits >> c) & 1u;
    unsigned long long kept = 0;
    #pragma unroll
    for (int i = 0; i < 64; ++i) {
      unsigned long long r64 = __ballot(rem_l != 0u);
      unsigned long long bit = 1ull << i;
      bool keep_i = (!(r64 & bit)) && (sp & bit);  // wave-uniform
      if (keep_i) {
        kept |= bit;
        rem_l |= (unsigned)((col_l >> i) & 1ull);
      }
    }
    // apply suppression by this chunk's kept rows to future chunks
    #define APP(K_, CW_) if (K_ > c && ((CW_) & kept)) removedbits |= (1u << K_)
    APP(0, cw0);  APP(1, cw1);  APP(2, cw2);  APP(3, cw3);
    APP(4, cw4);  APP(5, cw5);  APP(6, cw6);  APP(7, cw7);
    APP(8, cw8);  APP(9, cw9);  APP(10, cw10); APP(11, cw11);
    APP(12, cw12); APP(13, cw13); APP(14, cw14); APP(15, cw15);
    #undef APP
    removedbits = (removedbits & ~(1u << c)) | (rem_l << c);
  }
  #pragma unroll
  for (int k = 0; k < 16; ++k) {
    unsigned long long w = __ballot(((removedbits >> k) & 1u) != 0u);
    if (l == 0) keepmask[(size_t)n * 16 + k] = w;
  }
}

__global__ __launch_bounds__(1024) void finalize_kernel(
    const unsigned long long* __restrict__ keepmask, const float* __restrict__ tscores,
    const float* __restrict__ tboxes, const int* __restrict__ tlabels,
    float* __restrict__ out)
{
  int n = blockIdx.x;
  int tid = threadIdx.x;
  __shared__ unsigned sk[1024];
  __shared__ unsigned sz[1024];
  bool inr = (tid < PRE_K);
  bool keep = false; float sc = 0.f;
  if (inr) {
    unsigned long long w = keepmask[(size_t)n * 16 + (tid >> 6)];
    bool rem = (w >> (tid & 63)) & 1ull;
    sc = tscores[(size_t)n * PRE_K + tid];
    keep = (!rem) && (sc > 0.f);
  }
  sk[tid] = keep ? 1u : 0u;
  sz[tid] = (inr && !keep) ? 1u : 0u;
  __syncthreads();
  for (int ofs = 1; ofs < 1024; ofs <<= 1) {
    unsigned a = (tid >= ofs) ? sk[tid - ofs] : 0;
    unsigned b = (tid >= ofs) ? sz[tid - ofs] : 0;
    __syncthreads();
    sk[tid] += a; sz[tid] += b;
    __syncthreads();
  }
  int nk = (int)sk[1023];
  int slot = -1;
  if (inr) {
    if (keep) {
      int r = (int)sk[tid] - 1;
      if (r < POST_K) slot = r;
    } else {
      int r = nk + (int)sz[tid] - 1;
      if (r < POST_K) slot = r;
    }
  }
  if (slot >= 0) {
    size_t src = (size_t)n * PRE_K + tid;
    size_t ob = ((size_t)n * POST_K + slot) * 4;
    out[ob+0] = tboxes[4*src+0];
    out[ob+1] = tboxes[4*src+1];
    out[ob+2] = tboxes[4*src+2];
    out[ob+3] = tboxes[4*src+3];
    out[(size_t)NB*POST_K*4 + (size_t)n*POST_K + slot] = keep ? sc : 0.0f;
    out[(size_t)NB*POST_K*5 + (size_t)n*POST_K + slot] = (float)tlabels[src];
  }
}

extern "C" void kernel_launch(void* const* d_in, const int* in_sizes, int n_in,
                              void* d_out, int out_size, void* d_ws, size_t ws_size,
                              hipStream_t stream) {
  char* w = (char*)d_ws;
  auto carve = [&](size_t bytes) { char* p = w; w += (bytes + 255) & ~(size_t)255; return p; };
  float* scores = (float*)carve((size_t)NB * P_TOT * 4);
  int* labels   = (int*)carve((size_t)NB * P_TOT * 4);
  float* boxes  = (float*)carve((size_t)NB * P_TOT * 16);
  unsigned long long* keys    = (unsigned long long*)carve((size_t)NB * P_TOT * 8);
  unsigned long long* topkeys = (unsigned long long*)carve((size_t)NB * 1024 * 8);
  float* tboxes  = (float*)carve((size_t)NB * PRE_K * 16);
  float* tscores = (float*)carve((size_t)NB * PRE_K * 4);
  int* tlabels   = (int*)carve((size_t)NB * PRE_K * 4);
  unsigned long long* colsupp  = (unsigned long long*)carve((size_t)NB * PRE_K * 16 * 8);
  unsigned long long* keepmask = (unsigned long long*)carve((size_t)NB * 16 * 8);

  const float* cls0 = (const float*)d_in[0];
  const float* reg0 = (const float*)d_in[1];
  const float* ctr0 = (const float*)d_in[2];
  const float* cls1 = (const float*)d_in[3];
  const float* reg1 = (const float*)d_in[4];
  const float* ctr1 = (const float*)d_in[5];
  const float* cls2 = (const float*)d_in[6];
  const float* reg2 = (const float*)d_in[7];
  const float* ctr2 = (const float*)d_in[8];
  const float* cls3 = (const float*)d_in[9];
  const float* reg3 = (const float*)d_in[10];
  const float* ctr3 = (const float*)d_in[11];
  const float* cls4 = (const float*)d_in[12];
  const float* reg4 = (const float*)d_in[13];
  const float* ctr4 = (const float*)d_in[14];

  dim3 dg((P4 + 255) / 256, NB);
  decode_kernel<<<dg, 256, 0, stream>>>(cls0, reg0, ctr0, cls1, reg1, ctr1,
                                        cls2, reg2, ctr2, cls3, reg3, ctr3,
                                        cls4, reg4, ctr4,
                                        scores, labels, boxes, keys);
  topk_kernel<<<NB, 1024, 0, stream>>>(keys, topkeys);
  gather_kernel<<<(NB * PRE_K + 255) / 256, 256, 0, stream>>>(topkeys, boxes, labels,
                                                              tboxes, tscores, tlabels);
  dim3 gi((PRE_K + 127) / 128, NB);
  iou_kernel<<<gi, 128, 0, stream>>>(tboxes, tlabels, colsupp);
  greedy_kernel<<<NB, 64, 0, stream>>>(colsupp, tscores, keepmask);
  finalize_kernel<<<NB, 1024, 0, stream>>>(keepmask, tscores, tboxes, tlabels, (float*)d_out);
}

// Round 3
// 204.244 us; speedup vs baseline: 2.3107x; 1.8103x over previous
//
#include <hip/hip_runtime.h>
#include <stdint.h>

#pragma clang fp contract(off)

#define NB 16
#define NC 80
#define P_TOT 17064
#define P4 (P_TOT / 4)
#define PRE_K 1000
#define POST_K 100

__device__ __forceinline__ float sigmoidf_(float x) {
  return 1.0f / (1.0f + expf(-x));
}

// 4 locations per thread, float4 loads. 4-packs never straddle a level or a row.
__global__ __launch_bounds__(256) void decode_kernel(
    const float* __restrict__ cls0, const float* __restrict__ reg0, const float* __restrict__ ctr0,
    const float* __restrict__ cls1, const float* __restrict__ reg1, const float* __restrict__ ctr1,
    const float* __restrict__ cls2, const float* __restrict__ reg2, const float* __restrict__ ctr2,
    const float* __restrict__ cls3, const float* __restrict__ reg3, const float* __restrict__ ctr3,
    const float* __restrict__ cls4, const float* __restrict__ reg4, const float* __restrict__ ctr4,
    float* __restrict__ scores, int* __restrict__ labels, float* __restrict__ boxes,
    unsigned long long* __restrict__ keys)
{
  int t = blockIdx.x * blockDim.x + threadIdx.x;
  int n = blockIdx.y;
  if (t >= P4) return;
  int p0 = t * 4;
  int off, wsh, hw; float stride; const float *cls, *reg, *ctr;
  if (p0 < 12800)      { off = 0;     wsh = 7; hw = 12800; stride = 8.f;   cls = cls0; reg = reg0; ctr = ctr0; }
  else if (p0 < 16000) { off = 12800; wsh = 6; hw = 3200;  stride = 16.f;  cls = cls1; reg = reg1; ctr = ctr1; }
  else if (p0 < 16800) { off = 16000; wsh = 5; hw = 800;   stride = 32.f;  cls = cls2; reg = reg2; ctr = ctr2; }
  else if (p0 < 17008) { off = 16800; wsh = 4; hw = 208;   stride = 64.f;  cls = cls3; reg = reg3; ctr = ctr3; }
  else                 { off = 17008; wsh = 3; hw = 56;    stride = 128.f; cls = cls4; reg = reg4; ctr = ctr4; }
  int loc0 = p0 - off;
  int y = loc0 >> wsh;
  int x0 = loc0 & ((1 << wsh) - 1);
  float py = (float)y * stride + 0.5f * stride;

  float4 c4 = *reinterpret_cast<const float4*>(ctr + (size_t)n * hw + loc0);
  float sctr[4] = { sigmoidf_(c4.x), sigmoidf_(c4.y), sigmoidf_(c4.z), sigmoidf_(c4.w) };

  const float* cbase = cls + (size_t)n * NC * hw + loc0;
  float best[4] = { -1.f, -1.f, -1.f, -1.f };
  int bl[4] = { 0, 0, 0, 0 };
  for (int c = 0; c < NC; ++c) {
    float4 cv = *reinterpret_cast<const float4*>(cbase + (size_t)c * hw);
    float v;
    v = sqrtf(sigmoidf_(cv.x) * sctr[0]); if (v > best[0]) { best[0] = v; bl[0] = c; }
    v = sqrtf(sigmoidf_(cv.y) * sctr[1]); if (v > best[1]) { best[1] = v; bl[1] = c; }
    v = sqrtf(sigmoidf_(cv.z) * sctr[2]); if (v > best[2]) { best[2] = v; bl[2] = c; }
    v = sqrtf(sigmoidf_(cv.w) * sctr[3]); if (v > best[3]) { best[3] = v; bl[3] = c; }
  }

  const float* rbase = reg + (size_t)n * 4 * hw + loc0;
  float4 rl = *reinterpret_cast<const float4*>(rbase);
  float4 rt = *reinterpret_cast<const float4*>(rbase + (size_t)hw);
  float4 rr = *reinterpret_cast<const float4*>(rbase + (size_t)2 * hw);
  float4 rb = *reinterpret_cast<const float4*>(rbase + (size_t)3 * hw);
  float dl[4] = { rl.x, rl.y, rl.z, rl.w };
  float dt[4] = { rt.x, rt.y, rt.z, rt.w };
  float dr[4] = { rr.x, rr.y, rr.z, rr.w };
  float db[4] = { rb.x, rb.y, rb.z, rb.w };

  size_t o0 = (size_t)n * P_TOT + p0;
  float4 val4; float* valp = &val4.x;
  int4 bl4; int* blp = &bl4.x;
  unsigned long long kk[4];
  #pragma unroll
  for (int e = 0; e < 4; ++e) {
    float px = (float)(x0 + e) * stride + 0.5f * stride;
    float val = (best[e] > 0.05f) ? best[e] : 0.0f;
    float x1 = fminf(fmaxf(px - dl[e], 0.f), 1024.f);
    float y1 = fminf(fmaxf(py - dt[e], 0.f), 800.f);
    float x2 = fminf(fmaxf(px + dr[e], 0.f), 1024.f);
    float y2 = fminf(fmaxf(py + db[e], 0.f), 800.f);
    valp[e] = val;
    blp[e] = bl[e];
    *reinterpret_cast<float4*>(boxes + 4 * (o0 + e)) = make_float4(x1, y1, x2, y2);
    kk[e] = ((unsigned long long)__float_as_uint(val) << 32)
          | (unsigned long long)(0xFFFFFFFFu - (unsigned)(p0 + e));
  }
  *reinterpret_cast<float4*>(scores + o0) = val4;
  *reinterpret_cast<int4*>(labels + o0) = bl4;
  ulonglong2 k01; k01.x = kk[0]; k01.y = kk[1];
  ulonglong2 k23; k23.x = kk[2]; k23.y = kk[3];
  *reinterpret_cast<ulonglong2*>(keys + o0) = k01;
  *reinterpret_cast<ulonglong2*>(keys + o0 + 2) = k23;
}

// One block per batch: exact top-1000 (desc by key) via MSB radix select + bitonic sort.
// Per-wave histograms (pitch 257 breaks bank aliasing) + parallel suffix-scan digit pick.
__global__ __launch_bounds__(1024) void topk_kernel(
    const unsigned long long* __restrict__ keys, unsigned long long* __restrict__ topkeys)
{
  int n = blockIdx.x;
  int tid = threadIdx.x;
  int wave = tid >> 6;
  int lane = tid & 63;
  __shared__ unsigned histW[16 * 257];
  __shared__ unsigned hist[256];
  __shared__ unsigned s_digit, s_Knext, s_cnt;
  __shared__ unsigned long long skey[1024];
  const unsigned long long* bk = keys + (size_t)n * P_TOT;

  unsigned long long pfx = 0ULL;
  unsigned K = PRE_K;
  for (int pass = 0; pass < 8; ++pass) {
    int shift = 56 - 8 * pass;
    unsigned long long mask = (pass == 0) ? 0ULL : (~0ULL << (64 - 8 * pass));
    for (int d = tid; d < 16 * 257; d += 1024) histW[d] = 0;
    __syncthreads();
    for (int p = tid; p < P_TOT; p += 1024) {
      unsigned long long k = bk[p];
      if ((k & mask) == pfx)
        atomicAdd(&histW[wave * 257 + ((unsigned)(k >> shift) & 255u)], 1u);
    }
    __syncthreads();
    if (tid < 256) {
      unsigned s = 0;
      for (int w2 = 0; w2 < 16; ++w2) s += histW[w2 * 257 + tid];
      hist[tid] = s;
    }
    __syncthreads();
    // suffix inclusive sum: hist[d] = sum_{d'>=d}
    for (int ofs = 1; ofs < 256; ofs <<= 1) {
      unsigned v = 0;
      if (tid < 256) { v = hist[tid]; if (tid + ofs < 256) v += hist[tid + ofs]; }
      __syncthreads();
      if (tid < 256) hist[tid] = v;
      __syncthreads();
    }
    if (tid < 256) {
      unsigned S = hist[tid];
      unsigned Snext = (tid < 255) ? hist[tid + 1] : 0u;
      if (S >= K && Snext < K) { s_digit = (unsigned)tid; s_Knext = K - Snext; }
    }
    __syncthreads();
    pfx |= ((unsigned long long)s_digit << shift);
    K = s_Knext;
    __syncthreads();
  }
  unsigned long long kth = pfx;
  skey[tid] = 0ULL;
  if (tid == 0) s_cnt = 0;
  __syncthreads();
  for (int p = tid; p < P_TOT; p += 1024) {
    unsigned long long k = bk[p];
    bool take = (k >= kth);
    unsigned long long b = __ballot(take);
    if (b) {
      int leader = __ffsll((unsigned long long)b) - 1;
      unsigned base = 0;
      if (lane == leader) base = atomicAdd(&s_cnt, (unsigned)__popcll(b));
      base = (unsigned)__shfl((int)base, leader);
      if (take) {
        unsigned pos = base + (unsigned)__popcll(b & ((1ull << lane) - 1ull));
        if (pos < 1024) skey[pos] = k;
      }
    }
  }
  __syncthreads();
  // bitonic sort, descending
  for (int k2 = 2; k2 <= 1024; k2 <<= 1) {
    for (int j = k2 >> 1; j > 0; j >>= 1) {
      int ixj = tid ^ j;
      if (ixj > tid) {
        unsigned long long a = skey[tid], b = skey[ixj];
        bool sw = ((tid & k2) == 0) ? (a < b) : (a > b);
        if (sw) { skey[tid] = b; skey[ixj] = a; }
      }
      __syncthreads();
    }
  }
  topkeys[(size_t)n * 1024 + tid] = skey[tid];
}

__global__ __launch_bounds__(256) void gather_kernel(
    const unsigned long long* __restrict__ topkeys,
    const float* __restrict__ boxes, const int* __restrict__ labels,
    float* __restrict__ tboxes, float* __restrict__ tscores, int* __restrict__ tlabels)
{
  int i = blockIdx.x * 256 + threadIdx.x;
  if (i >= NB * PRE_K) return;
  int n = i / PRE_K;
  int r = i - n * PRE_K;
  unsigned long long k = topkeys[(size_t)n * 1024 + r];
  unsigned idx = 0xFFFFFFFFu - (unsigned)(k & 0xFFFFFFFFu);
  float sc = __uint_as_float((unsigned)(k >> 32));
  size_t src = (size_t)n * P_TOT + idx;
  tscores[i] = sc;
  tlabels[i] = labels[src];
  tboxes[4*(size_t)i+0] = boxes[4*src+0];
  tboxes[4*(size_t)i+1] = boxes[4*src+1];
  tboxes[4*(size_t)i+2] = boxes[4*src+2];
  tboxes[4*(size_t)i+3] = boxes[4*src+3];
}

// COLUMN-major suppression, throughput-shaped.
// grid = (8 j-tiles, 16 i-words, NB).  Thread (jb*128+tid) computes the 64-bit
// word w of column j: bit b set iff i=w*64+b < j and IoU(offset boxes) > 0.6.
// No label test needed: the reference has none either — the +label*4096 offset
// guarantees different-label pairs have zero intersection (coords < 4096/2).
__global__ __launch_bounds__(128) void iou_kernel(
    const float* __restrict__ tboxes, const int* __restrict__ tlabels,
    unsigned long long* __restrict__ colsupp)
{
  int jb = blockIdx.x, w = blockIdx.y, n = blockIdx.z;
  int tid = threadIdx.x;
  int j = jb * 128 + tid;
  bool jvalid = (j < PRE_K);

  // Entirely above the diagonal: all bits masked (i >= j) -> zero word.
  if (w * 64 >= jb * 128 + 128) {
    if (jvalid) colsupp[((size_t)n * PRE_K + j) * 16 + w] = 0ULL;
    return;
  }

  __shared__ float4 sb[64];
  if (tid < 64) {
    int i = w * 64 + tid;
    float4 v = make_float4(0.f, 0.f, 0.f, 0.f);
    if (i < PRE_K) {
      const float* b = tboxes + ((size_t)n * PRE_K + i) * 4;
      float offv = (float)tlabels[(size_t)n * PRE_K + i] * 4096.0f;
      v = make_float4(b[0] + offv, b[1] + offv, b[2] + offv, b[3] + offv);
    }
    sb[tid] = v;
  }
  __syncthreads();

  float4 bj = make_float4(0.f, 0.f, 0.f, 0.f);
  if (jvalid) {
    const float* b = tboxes + ((size_t)n * PRE_K + j) * 4;
    float offv = (float)tlabels[(size_t)n * PRE_K + j] * 4096.0f;
    bj = make_float4(b[0] + offv, b[1] + offv, b[2] + offv, b[3] + offv);
  }
  float aj = (bj.z - bj.x) * (bj.w - bj.y);

  unsigned long long m = 0;
  int ibase = w * 64;
  #pragma unroll
  for (int b = 0; b < 64; ++b) {
    float4 bi = sb[b];
    float ai = (bi.z - bi.x) * (bi.w - bi.y);
    float lx = fmaxf(bi.x, bj.x), ly = fmaxf(bi.y, bj.y);
    float rx = fminf(bi.z, bj.z), ry = fminf(bi.w, bj.w);
    float iw = fmaxf(rx - lx, 0.f), ih = fmaxf(ry - ly, 0.f);
    float inter = iw * ih;
    float iou = inter / (ai + aj - inter + 1e-9f);
    if (iou > 0.6f && (ibase + b) < j) m |= (1ull << b);
  }
  if (jvalid) colsupp[((size_t)n * PRE_K + j) * 16 + w] = m;
}

// One wave per batch. Column-distributed removed state; within-chunk recurrence
// uses __ballot (register/SALU critical path, no shfl/LDS/global on the chain).
__global__ __launch_bounds__(64) void greedy_kernel(
    const unsigned long long* __restrict__ colsupp, const float* __restrict__ tscores,
    unsigned long long* __restrict__ keepmask)
{
  int n = blockIdx.x;
  int l = threadIdx.x;
  const unsigned long long* C = colsupp + (size_t)n * PRE_K * 16;
  const float* sc = tscores + (size_t)n * PRE_K;
  unsigned removedbits = 0;  // bit k: column index k*64+l removed

  for (int c = 0; c < 16; ++c) {
    int j = c * 64 + l;
    bool valid = (j < PRE_K);
    float s_l = valid ? sc[j] : 0.f;
    unsigned long long col_l = valid ? C[(size_t)j * 16 + c] : 0ULL;
    // cross-chunk words: static 16-unroll so all loads pipeline (no scratch)
    unsigned long long cw0, cw1, cw2, cw3, cw4, cw5, cw6, cw7;
    unsigned long long cw8, cw9, cw10, cw11, cw12, cw13, cw14, cw15;
    {
      #define LDW(K_) ((K_ * 64 + l) < PRE_K ? C[(size_t)(K_ * 64 + l) * 16 + c] : 0ULL)
      cw0 = LDW(0);  cw1 = LDW(1);  cw2 = LDW(2);  cw3 = LDW(3);
      cw4 = LDW(4);  cw5 = LDW(5);  cw6 = LDW(6);  cw7 = LDW(7);
      cw8 = LDW(8);  cw9 = LDW(9);  cw10 = LDW(10); cw11 = LDW(11);
      cw12 = LDW(12); cw13 = LDW(13); cw14 = LDW(14); cw15 = LDW(15);
      #undef LDW
    }
    unsigned long long sp = __ballot(s_l > 0.f);
    unsigned rem_l = (removedbits >> c) & 1u;
    unsigned long long kept = 0;
    #pragma unroll
    for (int i = 0; i < 64; ++i) {
      unsigned long long r64 = __ballot(rem_l != 0u);
      unsigned long long bit = 1ull << i;
      bool keep_i = (!(r64 & bit)) && (sp & bit);  // wave-uniform
      if (keep_i) {
        kept |= bit;
        rem_l |= (unsigned)((col_l >> i) & 1ull);
      }
    }
    // apply suppression by this chunk's kept rows to future chunks
    #define APP(K_, CW_) if (K_ > c && ((CW_) & kept)) removedbits |= (1u << K_)
    APP(0, cw0);  APP(1, cw1);  APP(2, cw2);  APP(3, cw3);
    APP(4, cw4);  APP(5, cw5);  APP(6, cw6);  APP(7, cw7);
    APP(8, cw8);  APP(9, cw9);  APP(10, cw10); APP(11, cw11);
    APP(12, cw12); APP(13, cw13); APP(14, cw14); APP(15, cw15);
    #undef APP
    removedbits = (removedbits & ~(1u << c)) | (rem_l << c);
  }
  #pragma unroll
  for (int k = 0; k < 16; ++k) {
    unsigned long long w = __ballot(((removedbits >> k) & 1u) != 0u);
    if (l == 0) keepmask[(size_t)n * 16 + k] = w;
  }
}

__global__ __launch_bounds__(1024) void finalize_kernel(
    const unsigned long long* __restrict__ keepmask, const float* __restrict__ tscores,
    const float* __restrict__ tboxes, const int* __restrict__ tlabels,
    float* __restrict__ out)
{
  int n = blockIdx.x;
  int tid = threadIdx.x;
  __shared__ unsigned sk[1024];
  __shared__ unsigned sz[1024];
  bool inr = (tid < PRE_K);
  bool keep = false; float sc = 0.f;
  if (inr) {
    unsigned long long w = keepmask[(size_t)n * 16 + (tid >> 6)];
    bool rem = (w >> (tid & 63)) & 1ull;
    sc = tscores[(size_t)n * PRE_K + tid];
    keep = (!rem) && (sc > 0.f);
  }
  sk[tid] = keep ? 1u : 0u;
  sz[tid] = (inr && !keep) ? 1u : 0u;
  __syncthreads();
  for (int ofs = 1; ofs < 1024; ofs <<= 1) {
    unsigned a = (tid >= ofs) ? sk[tid - ofs] : 0;
    unsigned b = (tid >= ofs) ? sz[tid - ofs] : 0;
    __syncthreads();
    sk[tid] += a; sz[tid] += b;
    __syncthreads();
  }
  int nk = (int)sk[1023];
  int slot = -1;
  if (inr) {
    if (keep) {
      int r = (int)sk[tid] - 1;
      if (r < POST_K) slot = r;
    } else {
      int r = nk + (int)sz[tid] - 1;
      if (r < POST_K) slot = r;
    }
  }
  if (slot >= 0) {
    size_t src = (size_t)n * PRE_K + tid;
    size_t ob = ((size_t)n * POST_K + slot) * 4;
    out[ob+0] = tboxes[4*src+0];
    out[ob+1] = tboxes[4*src+1];
    out[ob+2] = tboxes[4*src+2];
    out[ob+3] = tboxes[4*src+3];
    out[(size_t)NB*POST_K*4 + (size_t)n*POST_K + slot] = keep ? sc : 0.0f;
    out[(size_t)NB*POST_K*5 + (size_t)n*POST_K + slot] = (float)tlabels[src];
  }
}

extern "C" void kernel_launch(void* const* d_in, const int* in_sizes, int n_in,
                              void* d_out, int out_size, void* d_ws, size_t ws_size,
                              hipStream_t stream) {
  char* w = (char*)d_ws;
  auto carve = [&](size_t bytes) { char* p = w; w += (bytes + 255) & ~(size_t)255; return p; };
  float* scores = (float*)carve((size_t)NB * P_TOT * 4);
  int* labels   = (int*)carve((size_t)NB * P_TOT * 4);
  float* boxes  = (float*)carve((size_t)NB * P_TOT * 16);
  unsigned long long* keys    = (unsigned long long*)carve((size_t)NB * P_TOT * 8);
  unsigned long long* topkeys = (unsigned long long*)carve((size_t)NB * 1024 * 8);
  float* tboxes  = (float*)carve((size_t)NB * PRE_K * 16);
  float* tscores = (float*)carve((size_t)NB * PRE_K * 4);
  int* tlabels   = (int*)carve((size_t)NB * PRE_K * 4);
  unsigned long long* colsupp  = (unsigned long long*)carve((size_t)NB * PRE_K * 16 * 8);
  unsigned long long* keepmask = (unsigned long long*)carve((size_t)NB * 16 * 8);

  const float* cls0 = (const float*)d_in[0];
  const float* reg0 = (const float*)d_in[1];
  const float* ctr0 = (const float*)d_in[2];
  const float* cls1 = (const float*)d_in[3];
  const float* reg1 = (const float*)d_in[4];
  const float* ctr1 = (const float*)d_in[5];
  const float* cls2 = (const float*)d_in[6];
  const float* reg2 = (const float*)d_in[7];
  const float* ctr2 = (const float*)d_in[8];
  const float* cls3 = (const float*)d_in[9];
  const float* reg3 = (const float*)d_in[10];
  const float* ctr3 = (const float*)d_in[11];
  const float* cls4 = (const float*)d_in[12];
  const float* reg4 = (const float*)d_in[13];
  const float* ctr4 = (const float*)d_in[14];

  dim3 dg((P4 + 255) / 256, NB);
  decode_kernel<<<dg, 256, 0, stream>>>(cls0, reg0, ctr0, cls1, reg1, ctr1,
                                        cls2, reg2, ctr2, cls3, reg3, ctr3,
                                        cls4, reg4, ctr4,
                                        scores, labels, boxes, keys);
  topk_kernel<<<NB, 1024, 0, stream>>>(keys, topkeys);
  gather_kernel<<<(NB * PRE_K + 255) / 256, 256, 0, stream>>>(topkeys, boxes, labels,
                                                              tboxes, tscores, tlabels);
  dim3 gi(8, 16, NB);
  iou_kernel<<<gi, 128, 0, stream>>>(tboxes, tlabels, colsupp);
  greedy_kernel<<<NB, 64, 0, stream>>>(colsupp, tscores, keepmask);
  finalize_kernel<<<NB, 1024, 0, stream>>>(keepmask, tscores, tboxes, tlabels, (float*)d_out);
}

// Round 4
// 162.514 us; speedup vs baseline: 2.9041x; 1.2568x over previous
//
#include <hip/hip_runtime.h>
#include <stdint.h>

#pragma clang fp contract(off)

#define NB 16
#define NC 80
#define P_TOT 17064
#define P4 (P_TOT / 4)
#define PRE_K 1000
#define POST_K 100

__device__ __forceinline__ float sigmoidf_(float x) {
  return 1.0f / (1.0f + expf(-x));
}

// Class-split decode: each 4-lane quad owns a 4-location group; lane t4 covers
// classes [20*t4, 20*t4+20). Exact per-class math, shfl-reduce with lower-label
// tie-break (== numpy argmax first-max semantics). Lane t4==0 writes.
__global__ __launch_bounds__(256) void decode_kernel(
    const float* __restrict__ cls0, const float* __restrict__ reg0, const float* __restrict__ ctr0,
    const float* __restrict__ cls1, const float* __restrict__ reg1, const float* __restrict__ ctr1,
    const float* __restrict__ cls2, const float* __restrict__ reg2, const float* __restrict__ ctr2,
    const float* __restrict__ cls3, const float* __restrict__ reg3, const float* __restrict__ ctr3,
    const float* __restrict__ cls4, const float* __restrict__ reg4, const float* __restrict__ ctr4,
    float* __restrict__ scores, int* __restrict__ labels, float* __restrict__ boxes,
    unsigned long long* __restrict__ keys)
{
  int quad = blockIdx.x * 64 + (threadIdx.x >> 2);
  int t4 = threadIdx.x & 3;
  int n = blockIdx.y;
  if (quad >= P4) return;
  int p0 = quad * 4;
  int off, wsh, hw; float stride; const float *cls, *reg, *ctr;
  if (p0 < 12800)      { off = 0;     wsh = 7; hw = 12800; stride = 8.f;   cls = cls0; reg = reg0; ctr = ctr0; }
  else if (p0 < 16000) { off = 12800; wsh = 6; hw = 3200;  stride = 16.f;  cls = cls1; reg = reg1; ctr = ctr1; }
  else if (p0 < 16800) { off = 16000; wsh = 5; hw = 800;   stride = 32.f;  cls = cls2; reg = reg2; ctr = ctr2; }
  else if (p0 < 17008) { off = 16800; wsh = 4; hw = 208;   stride = 64.f;  cls = cls3; reg = reg3; ctr = ctr3; }
  else                 { off = 17008; wsh = 3; hw = 56;    stride = 128.f; cls = cls4; reg = reg4; ctr = ctr4; }
  int loc0 = p0 - off;
  int y = loc0 >> wsh;
  int x0 = loc0 & ((1 << wsh) - 1);
  float py = (float)y * stride + 0.5f * stride;

  float4 c4 = *reinterpret_cast<const float4*>(ctr + (size_t)n * hw + loc0);
  float sctr[4] = { sigmoidf_(c4.x), sigmoidf_(c4.y), sigmoidf_(c4.z), sigmoidf_(c4.w) };

  int c0 = t4 * 20;
  const float* cptr = cls + (size_t)n * NC * hw + (size_t)c0 * hw + loc0;
  float best[4] = { -1.f, -1.f, -1.f, -1.f };
  int bl[4] = { 0, 0, 0, 0 };
  #pragma unroll 5
  for (int k = 0; k < 20; ++k) {
    float4 cv = *reinterpret_cast<const float4*>(cptr + (size_t)k * hw);
    int c = c0 + k;
    float v;
    v = sqrtf(sigmoidf_(cv.x) * sctr[0]); if (v > best[0]) { best[0] = v; bl[0] = c; }
    v = sqrtf(sigmoidf_(cv.y) * sctr[1]); if (v > best[1]) { best[1] = v; bl[1] = c; }
    v = sqrtf(sigmoidf_(cv.z) * sctr[2]); if (v > best[2]) { best[2] = v; bl[2] = c; }
    v = sqrtf(sigmoidf_(cv.w) * sctr[3]); if (v > best[3]) { best[3] = v; bl[3] = c; }
  }

  // reduce across the quad (lanes t4=0..3): max, tie -> lower label
  #pragma unroll
  for (int e = 0; e < 4; ++e) {
    #pragma unroll
    for (int d = 1; d <= 2; d <<= 1) {
      float ob = __shfl_xor(best[e], d);
      int ol = __shfl_xor(bl[e], d);
      if (ob > best[e] || (ob == best[e] && ol < bl[e])) { best[e] = ob; bl[e] = ol; }
    }
  }
  if (t4 != 0) return;

  const float* rbase = reg + (size_t)n * 4 * hw + loc0;
  float4 rl = *reinterpret_cast<const float4*>(rbase);
  float4 rt = *reinterpret_cast<const float4*>(rbase + (size_t)hw);
  float4 rr = *reinterpret_cast<const float4*>(rbase + (size_t)2 * hw);
  float4 rb = *reinterpret_cast<const float4*>(rbase + (size_t)3 * hw);
  float dl[4] = { rl.x, rl.y, rl.z, rl.w };
  float dt[4] = { rt.x, rt.y, rt.z, rt.w };
  float dr[4] = { rr.x, rr.y, rr.z, rr.w };
  float db[4] = { rb.x, rb.y, rb.z, rb.w };

  size_t o0 = (size_t)n * P_TOT + p0;
  float4 val4; float* valp = &val4.x;
  int4 bl4; int* blp = &bl4.x;
  unsigned long long kk[4];
  #pragma unroll
  for (int e = 0; e < 4; ++e) {
    float px = (float)(x0 + e) * stride + 0.5f * stride;
    float val = (best[e] > 0.05f) ? best[e] : 0.0f;
    float x1 = fminf(fmaxf(px - dl[e], 0.f), 1024.f);
    float y1 = fminf(fmaxf(py - dt[e], 0.f), 800.f);
    float x2 = fminf(fmaxf(px + dr[e], 0.f), 1024.f);
    float y2 = fminf(fmaxf(py + db[e], 0.f), 800.f);
    valp[e] = val;
    blp[e] = bl[e];
    *reinterpret_cast<float4*>(boxes + 4 * (o0 + e)) = make_float4(x1, y1, x2, y2);
    kk[e] = ((unsigned long long)__float_as_uint(val) << 32)
          | (unsigned long long)(0xFFFFFFFFu - (unsigned)(p0 + e));
  }
  *reinterpret_cast<float4*>(scores + o0) = val4;
  *reinterpret_cast<int4*>(labels + o0) = bl4;
  ulonglong2 k01; k01.x = kk[0]; k01.y = kk[1];
  ulonglong2 k23; k23.x = kk[2]; k23.y = kk[3];
  *reinterpret_cast<ulonglong2*>(keys + o0) = k01;
  *reinterpret_cast<ulonglong2*>(keys + o0 + 2) = k23;
}

// One block per batch: exact top-1000 (desc by key) via MSB radix select + bitonic sort.
// Early-exit: once the selected digit's bin holds exactly 1 key, that key IS the kth;
// one find-scan retrieves it and the remaining passes are skipped.
__global__ __launch_bounds__(1024) void topk_kernel(
    const unsigned long long* __restrict__ keys, unsigned long long* __restrict__ topkeys)
{
  int n = blockIdx.x;
  int tid = threadIdx.x;
  int wave = tid >> 6;
  int lane = tid & 63;
  __shared__ unsigned histW[16 * 257];
  __shared__ unsigned hist[256];
  __shared__ unsigned s_digit, s_Knext, s_cbin, s_cnt;
  __shared__ unsigned long long s_kthkey;
  const unsigned long long* bk = keys + (size_t)n * P_TOT;

  unsigned long long pfx = 0ULL;
  unsigned K = PRE_K;
  bool have_kth = false;
  unsigned long long kth = 0ULL;
  for (int pass = 0; pass < 8; ++pass) {
    int shift = 56 - 8 * pass;
    unsigned long long mask = (pass == 0) ? 0ULL : (~0ULL << (64 - 8 * pass));
    for (int d = tid; d < 16 * 257; d += 1024) histW[d] = 0;
    __syncthreads();
    for (int p = tid; p < P_TOT; p += 1024) {
      unsigned long long k = bk[p];
      if ((k & mask) == pfx)
        atomicAdd(&histW[wave * 257 + ((unsigned)(k >> shift) & 255u)], 1u);
    }
    __syncthreads();
    if (tid < 256) {
      unsigned s = 0;
      for (int w2 = 0; w2 < 16; ++w2) s += histW[w2 * 257 + tid];
      hist[tid] = s;
    }
    __syncthreads();
    // suffix inclusive sum: hist[d] = sum_{d'>=d}
    for (int ofs = 1; ofs < 256; ofs <<= 1) {
      unsigned v = 0;
      if (tid < 256) { v = hist[tid]; if (tid + ofs < 256) v += hist[tid + ofs]; }
      __syncthreads();
      if (tid < 256) hist[tid] = v;
      __syncthreads();
    }
    if (tid < 256) {
      unsigned S = hist[tid];
      unsigned Snext = (tid < 255) ? hist[tid + 1] : 0u;
      if (S >= K && Snext < K) { s_digit = (unsigned)tid; s_Knext = K - Snext; s_cbin = S - Snext; }
    }
    __syncthreads();
    pfx |= ((unsigned long long)s_digit << shift);
    K = s_Knext;
    bool uniq = (s_cbin == 1u);
    __syncthreads();
    if (uniq) {
      if (pass == 7) { have_kth = true; kth = pfx; break; }
      unsigned long long m2 = ~0ULL << (56 - 8 * pass);  // full prefix incl. this digit
      for (int p = tid; p < P_TOT; p += 1024) {
        unsigned long long k = bk[p];
        if ((k & m2) == pfx) s_kthkey = k;
      }
      __syncthreads();
      kth = s_kthkey;
      have_kth = true;
      break;
    }
  }
  if (!have_kth) kth = pfx;

  __shared__ unsigned long long skey[1024];
  skey[tid] = 0ULL;
  if (tid == 0) s_cnt = 0;
  __syncthreads();
  for (int p = tid; p < P_TOT; p += 1024) {
    unsigned long long k = bk[p];
    bool take = (k >= kth);
    unsigned long long b = __ballot(take);
    if (b) {
      int leader = __ffsll((unsigned long long)b) - 1;
      unsigned base = 0;
      if (lane == leader) base = atomicAdd(&s_cnt, (unsigned)__popcll(b));
      base = (unsigned)__shfl((int)base, leader);
      if (take) {
        unsigned pos = base + (unsigned)__popcll(b & ((1ull << lane) - 1ull));
        if (pos < 1024) skey[pos] = k;
      }
    }
  }
  __syncthreads();
  // bitonic sort, descending
  for (int k2 = 2; k2 <= 1024; k2 <<= 1) {
    for (int j = k2 >> 1; j > 0; j >>= 1) {
      int ixj = tid ^ j;
      if (ixj > tid) {
        unsigned long long a = skey[tid], b = skey[ixj];
        bool sw = ((tid & k2) == 0) ? (a < b) : (a > b);
        if (sw) { skey[tid] = b; skey[ixj] = a; }
      }
      __syncthreads();
    }
  }
  topkeys[(size_t)n * 1024 + tid] = skey[tid];
}

__global__ __launch_bounds__(256) void gather_kernel(
    const unsigned long long* __restrict__ topkeys,
    const float* __restrict__ boxes, const int* __restrict__ labels,
    float* __restrict__ tboxes, float* __restrict__ tscores, int* __restrict__ tlabels)
{
  int i = blockIdx.x * 256 + threadIdx.x;
  if (i >= NB * PRE_K) return;
  int n = i / PRE_K;
  int r = i - n * PRE_K;
  unsigned long long k = topkeys[(size_t)n * 1024 + r];
  unsigned idx = 0xFFFFFFFFu - (unsigned)(k & 0xFFFFFFFFu);
  float sc = __uint_as_float((unsigned)(k >> 32));
  size_t src = (size_t)n * P_TOT + idx;
  tscores[i] = sc;
  tlabels[i] = labels[src];
  tboxes[4*(size_t)i+0] = boxes[4*src+0];
  tboxes[4*(size_t)i+1] = boxes[4*src+1];
  tboxes[4*(size_t)i+2] = boxes[4*src+2];
  tboxes[4*(size_t)i+3] = boxes[4*src+3];
}

// COLUMN-major suppression, throughput-shaped.
// grid = (8 j-tiles, 16 i-words, NB).  Thread (jb*128+tid) computes the 64-bit
// word w of column j: bit b set iff i=w*64+b < j and IoU(offset boxes) > 0.6.
// No label test needed: the +label*4096 offset guarantees different-label pairs
// have zero intersection (coords < 4096/2).
__global__ __launch_bounds__(128) void iou_kernel(
    const float* __restrict__ tboxes, const int* __restrict__ tlabels,
    unsigned long long* __restrict__ colsupp)
{
  int jb = blockIdx.x, w = blockIdx.y, n = blockIdx.z;
  int tid = threadIdx.x;
  int j = jb * 128 + tid;
  bool jvalid = (j < PRE_K);

  if (w * 64 >= jb * 128 + 128) {
    if (jvalid) colsupp[((size_t)n * PRE_K + j) * 16 + w] = 0ULL;
    return;
  }

  __shared__ float4 sb[64];
  if (tid < 64) {
    int i = w * 64 + tid;
    float4 v = make_float4(0.f, 0.f, 0.f, 0.f);
    if (i < PRE_K) {
      const float* b = tboxes + ((size_t)n * PRE_K + i) * 4;
      float offv = (float)tlabels[(size_t)n * PRE_K + i] * 4096.0f;
      v = make_float4(b[0] + offv, b[1] + offv, b[2] + offv, b[3] + offv);
    }
    sb[tid] = v;
  }
  __syncthreads();

  float4 bj = make_float4(0.f, 0.f, 0.f, 0.f);
  if (jvalid) {
    const float* b = tboxes + ((size_t)n * PRE_K + j) * 4;
    float offv = (float)tlabels[(size_t)n * PRE_K + j] * 4096.0f;
    bj = make_float4(b[0] + offv, b[1] + offv, b[2] + offv, b[3] + offv);
  }
  float aj = (bj.z - bj.x) * (bj.w - bj.y);

  unsigned long long m = 0;
  int ibase = w * 64;
  #pragma unroll
  for (int b = 0; b < 64; ++b) {
    float4 bi = sb[b];
    float ai = (bi.z - bi.x) * (bi.w - bi.y);
    float lx = fmaxf(bi.x, bj.x), ly = fmaxf(bi.y, bj.y);
    float rx = fminf(bi.z, bj.z), ry = fminf(bi.w, bj.w);
    float iw = fmaxf(rx - lx, 0.f), ih = fmaxf(ry - ly, 0.f);
    float inter = iw * ih;
    float iou = inter / (ai + aj - inter + 1e-9f);
    if (iou > 0.6f && (ibase + b) < j) m |= (1ull << b);
  }
  if (jvalid) colsupp[((size_t)n * PRE_K + j) * 16 + w] = m;
}

// One wave per batch. Column-distributed removed state; within-chunk recurrence
// uses __ballot (register/SALU critical path).
__global__ __launch_bounds__(64) void greedy_kernel(
    const unsigned long long* __restrict__ colsupp, const float* __restrict__ tscores,
    unsigned long long* __restrict__ keepmask)
{
  int n = blockIdx.x;
  int l = threadIdx.x;
  const unsigned long long* C = colsupp + (size_t)n * PRE_K * 16;
  const float* sc = tscores + (size_t)n * PRE_K;
  unsigned removedbits = 0;  // bit k: column index k*64+l removed

  for (int c = 0; c < 16; ++c) {
    int j = c * 64 + l;
    bool valid = (j < PRE_K);
    float s_l = valid ? sc[j] : 0.f;
    unsigned long long col_l = valid ? C[(size_t)j * 16 + c] : 0ULL;
    unsigned long long cw0, cw1, cw2, cw3, cw4, cw5, cw6, cw7;
    unsigned long long cw8, cw9, cw10, cw11, cw12, cw13, cw14, cw15;
    {
      #define LDW(K_) ((K_ * 64 + l) < PRE_K ? C[(size_t)(K_ * 64 + l) * 16 + c] : 0ULL)
      cw0 = LDW(0);  cw1 = LDW(1);  cw2 = LDW(2);  cw3 = LDW(3);
      cw4 = LDW(4);  cw5 = LDW(5);  cw6 = LDW(6);  cw7 = LDW(7);
      cw8 = LDW(8);  cw9 = LDW(9);  cw10 = LDW(10); cw11 = LDW(11);
      cw12 = LDW(12); cw13 = LDW(13); cw14 = LDW(14); cw15 = LDW(15);
      #undef LDW
    }
    unsigned long long sp = __ballot(s_l > 0.f);
    unsigned rem_l = (removedbits >> c) & 1u;
    unsigned long long kept = 0;
    #pragma unroll
    for (int i = 0; i < 64; ++i) {
      unsigned long long r64 = __ballot(rem_l != 0u);
      unsigned long long bit = 1ull << i;
      bool keep_i = (!(r64 & bit)) && (sp & bit);  // wave-uniform
      if (keep_i) {
        kept |= bit;
        rem_l |= (unsigned)((col_l >> i) & 1ull);
      }
    }
    #define APP(K_, CW_) if (K_ > c && ((CW_) & kept)) removedbits |= (1u << K_)
    APP(0, cw0);  APP(1, cw1);  APP(2, cw2);  APP(3, cw3);
    APP(4, cw4);  APP(5, cw5);  APP(6, cw6);  APP(7, cw7);
    APP(8, cw8);  APP(9, cw9);  APP(10, cw10); APP(11, cw11);
    APP(12, cw12); APP(13, cw13); APP(14, cw14); APP(15, cw15);
    #undef APP
    removedbits = (removedbits & ~(1u << c)) | (rem_l << c);
  }
  #pragma unroll
  for (int k = 0; k < 16; ++k) {
    unsigned long long w = __ballot(((removedbits >> k) & 1u) != 0u);
    if (l == 0) keepmask[(size_t)n * 16 + k] = w;
  }
}

__global__ __launch_bounds__(1024) void finalize_kernel(
    const unsigned long long* __restrict__ keepmask, const float* __restrict__ tscores,
    const float* __restrict__ tboxes, const int* __restrict__ tlabels,
    float* __restrict__ out)
{
  int n = blockIdx.x;
  int tid = threadIdx.x;
  __shared__ unsigned sk[1024];
  __shared__ unsigned sz[1024];
  bool inr = (tid < PRE_K);
  bool keep = false; float sc = 0.f;
  if (inr) {
    unsigned long long w = keepmask[(size_t)n * 16 + (tid >> 6)];
    bool rem = (w >> (tid & 63)) & 1ull;
    sc = tscores[(size_t)n * PRE_K + tid];
    keep = (!rem) && (sc > 0.f);
  }
  sk[tid] = keep ? 1u : 0u;
  sz[tid] = (inr && !keep) ? 1u : 0u;
  __syncthreads();
  for (int ofs = 1; ofs < 1024; ofs <<= 1) {
    unsigned a = (tid >= ofs) ? sk[tid - ofs] : 0;
    unsigned b = (tid >= ofs) ? sz[tid - ofs] : 0;
    __syncthreads();
    sk[tid] += a; sz[tid] += b;
    __syncthreads();
  }
  int nk = (int)sk[1023];
  int slot = -1;
  if (inr) {
    if (keep) {
      int r = (int)sk[tid] - 1;
      if (r < POST_K) slot = r;
    } else {
      int r = nk + (int)sz[tid] - 1;
      if (r < POST_K) slot = r;
    }
  }
  if (slot >= 0) {
    size_t src = (size_t)n * PRE_K + tid;
    size_t ob = ((size_t)n * POST_K + slot) * 4;
    out[ob+0] = tboxes[4*src+0];
    out[ob+1] = tboxes[4*src+1];
    out[ob+2] = tboxes[4*src+2];
    out[ob+3] = tboxes[4*src+3];
    out[(size_t)NB*POST_K*4 + (size_t)n*POST_K + slot] = keep ? sc : 0.0f;
    out[(size_t)NB*POST_K*5 + (size_t)n*POST_K + slot] = (float)tlabels[src];
  }
}

extern "C" void kernel_launch(void* const* d_in, const int* in_sizes, int n_in,
                              void* d_out, int out_size, void* d_ws, size_t ws_size,
                              hipStream_t stream) {
  char* w = (char*)d_ws;
  auto carve = [&](size_t bytes) { char* p = w; w += (bytes + 255) & ~(size_t)255; return p; };
  float* scores = (float*)carve((size_t)NB * P_TOT * 4);
  int* labels   = (int*)carve((size_t)NB * P_TOT * 4);
  float* boxes  = (float*)carve((size_t)NB * P_TOT * 16);
  unsigned long long* keys    = (unsigned long long*)carve((size_t)NB * P_TOT * 8);
  unsigned long long* topkeys = (unsigned long long*)carve((size_t)NB * 1024 * 8);
  float* tboxes  = (float*)carve((size_t)NB * PRE_K * 16);
  float* tscores = (float*)carve((size_t)NB * PRE_K * 4);
  int* tlabels   = (int*)carve((size_t)NB * PRE_K * 4);
  unsigned long long* colsupp  = (unsigned long long*)carve((size_t)NB * PRE_K * 16 * 8);
  unsigned long long* keepmask = (unsigned long long*)carve((size_t)NB * 16 * 8);

  const float* cls0 = (const float*)d_in[0];
  const float* reg0 = (const float*)d_in[1];
  const float* ctr0 = (const float*)d_in[2];
  const float* cls1 = (const float*)d_in[3];
  const float* reg1 = (const float*)d_in[4];
  const float* ctr1 = (const float*)d_in[5];
  const float* cls2 = (const float*)d_in[6];
  const float* reg2 = (const float*)d_in[7];
  const float* ctr2 = (const float*)d_in[8];
  const float* cls3 = (const float*)d_in[9];
  const float* reg3 = (const float*)d_in[10];
  const float* ctr3 = (const float*)d_in[11];
  const float* cls4 = (const float*)d_in[12];
  const float* reg4 = (const float*)d_in[13];
  const float* ctr4 = (const float*)d_in[14];

  dim3 dg((P4 + 63) / 64, NB);
  decode_kernel<<<dg, 256, 0, stream>>>(cls0, reg0, ctr0, cls1, reg1, ctr1,
                                        cls2, reg2, ctr2, cls3, reg3, ctr3,
                                        cls4, reg4, ctr4,
                                        scores, labels, boxes, keys);
  topk_kernel<<<NB, 1024, 0, stream>>>(keys, topkeys);
  gather_kernel<<<(NB * PRE_K + 255) / 256, 256, 0, stream>>>(topkeys, boxes, labels,
                                                              tboxes, tscores, tlabels);
  dim3 gi(8, 16, NB);
  iou_kernel<<<gi, 128, 0, stream>>>(tboxes, tlabels, colsupp);
  greedy_kernel<<<NB, 64, 0, stream>>>(colsupp, tscores, keepmask);
  finalize_kernel<<<NB, 1024, 0, stream>>>(keepmask, tscores, tboxes, tlabels, (float*)d_out);
}

// Round 5
// 123.897 us; speedup vs baseline: 3.8093x; 1.3117x over previous
//
#include <hip/hip_runtime.h>
#include <stdint.h>

#pragma clang fp contract(off)

#define NB 16
#define NC 80
#define P_TOT 17064
#define P4 (P_TOT / 4)
#define PRE_K 1000
#define POST_K 100

__device__ __forceinline__ float sigmoidf_(float x) {
  return 1.0f / (1.0f + expf(-x));
}

// Class-split decode: each 4-lane quad owns a 4-location group; lane t4 covers
// classes [20*t4, 20*t4+20). Exact per-class math, shfl-reduce with lower-label
// tie-break (== numpy argmax first-max semantics). Lane t4==0 writes.
__global__ __launch_bounds__(256) void decode_kernel(
    const float* __restrict__ cls0, const float* __restrict__ reg0, const float* __restrict__ ctr0,
    const float* __restrict__ cls1, const float* __restrict__ reg1, const float* __restrict__ ctr1,
    const float* __restrict__ cls2, const float* __restrict__ reg2, const float* __restrict__ ctr2,
    const float* __restrict__ cls3, const float* __restrict__ reg3, const float* __restrict__ ctr3,
    const float* __restrict__ cls4, const float* __restrict__ reg4, const float* __restrict__ ctr4,
    float* __restrict__ scores, int* __restrict__ labels, float* __restrict__ boxes,
    unsigned long long* __restrict__ keys)
{
  int quad = blockIdx.x * 64 + (threadIdx.x >> 2);
  int t4 = threadIdx.x & 3;
  int n = blockIdx.y;
  if (quad >= P4) return;
  int p0 = quad * 4;
  int off, wsh, hw; float stride; const float *cls, *reg, *ctr;
  if (p0 < 12800)      { off = 0;     wsh = 7; hw = 12800; stride = 8.f;   cls = cls0; reg = reg0; ctr = ctr0; }
  else if (p0 < 16000) { off = 12800; wsh = 6; hw = 3200;  stride = 16.f;  cls = cls1; reg = reg1; ctr = ctr1; }
  else if (p0 < 16800) { off = 16000; wsh = 5; hw = 800;   stride = 32.f;  cls = cls2; reg = reg2; ctr = ctr2; }
  else if (p0 < 17008) { off = 16800; wsh = 4; hw = 208;   stride = 64.f;  cls = cls3; reg = reg3; ctr = ctr3; }
  else                 { off = 17008; wsh = 3; hw = 56;    stride = 128.f; cls = cls4; reg = reg4; ctr = ctr4; }
  int loc0 = p0 - off;
  int y = loc0 >> wsh;
  int x0 = loc0 & ((1 << wsh) - 1);
  float py = (float)y * stride + 0.5f * stride;

  float4 c4 = *reinterpret_cast<const float4*>(ctr + (size_t)n * hw + loc0);
  float sctr[4] = { sigmoidf_(c4.x), sigmoidf_(c4.y), sigmoidf_(c4.z), sigmoidf_(c4.w) };

  int c0 = t4 * 20;
  const float* cptr = cls + (size_t)n * NC * hw + (size_t)c0 * hw + loc0;
  float best[4] = { -1.f, -1.f, -1.f, -1.f };
  int bl[4] = { 0, 0, 0, 0 };
  #pragma unroll 5
  for (int k = 0; k < 20; ++k) {
    float4 cv = *reinterpret_cast<const float4*>(cptr + (size_t)k * hw);
    int c = c0 + k;
    float v;
    v = sqrtf(sigmoidf_(cv.x) * sctr[0]); if (v > best[0]) { best[0] = v; bl[0] = c; }
    v = sqrtf(sigmoidf_(cv.y) * sctr[1]); if (v > best[1]) { best[1] = v; bl[1] = c; }
    v = sqrtf(sigmoidf_(cv.z) * sctr[2]); if (v > best[2]) { best[2] = v; bl[2] = c; }
    v = sqrtf(sigmoidf_(cv.w) * sctr[3]); if (v > best[3]) { best[3] = v; bl[3] = c; }
  }

  // reduce across the quad (lanes t4=0..3): max, tie -> lower label
  #pragma unroll
  for (int e = 0; e < 4; ++e) {
    #pragma unroll
    for (int d = 1; d <= 2; d <<= 1) {
      float ob = __shfl_xor(best[e], d);
      int ol = __shfl_xor(bl[e], d);
      if (ob > best[e] || (ob == best[e] && ol < bl[e])) { best[e] = ob; bl[e] = ol; }
    }
  }
  if (t4 != 0) return;

  const float* rbase = reg + (size_t)n * 4 * hw + loc0;
  float4 rl = *reinterpret_cast<const float4*>(rbase);
  float4 rt = *reinterpret_cast<const float4*>(rbase + (size_t)hw);
  float4 rr = *reinterpret_cast<const float4*>(rbase + (size_t)2 * hw);
  float4 rb = *reinterpret_cast<const float4*>(rbase + (size_t)3 * hw);
  float dl[4] = { rl.x, rl.y, rl.z, rl.w };
  float dt[4] = { rt.x, rt.y, rt.z, rt.w };
  float dr[4] = { rr.x, rr.y, rr.z, rr.w };
  float db[4] = { rb.x, rb.y, rb.z, rb.w };

  size_t o0 = (size_t)n * P_TOT + p0;
  float4 val4; float* valp = &val4.x;
  int4 bl4; int* blp = &bl4.x;
  unsigned long long kk[4];
  #pragma unroll
  for (int e = 0; e < 4; ++e) {
    float px = (float)(x0 + e) * stride + 0.5f * stride;
    float val = (best[e] > 0.05f) ? best[e] : 0.0f;
    float x1 = fminf(fmaxf(px - dl[e], 0.f), 1024.f);
    float y1 = fminf(fmaxf(py - dt[e], 0.f), 800.f);
    float x2 = fminf(fmaxf(px + dr[e], 0.f), 1024.f);
    float y2 = fminf(fmaxf(py + db[e], 0.f), 800.f);
    valp[e] = val;
    blp[e] = bl[e];
    *reinterpret_cast<float4*>(boxes + 4 * (o0 + e)) = make_float4(x1, y1, x2, y2);
    kk[e] = ((unsigned long long)__float_as_uint(val) << 32)
          | (unsigned long long)(0xFFFFFFFFu - (unsigned)(p0 + e));
  }
  *reinterpret_cast<float4*>(scores + o0) = val4;
  *reinterpret_cast<int4*>(labels + o0) = bl4;
  ulonglong2 k01; k01.x = kk[0]; k01.y = kk[1];
  ulonglong2 k23; k23.x = kk[2]; k23.y = kk[3];
  *reinterpret_cast<ulonglong2*>(keys + o0) = k01;
  *reinterpret_cast<ulonglong2*>(keys + o0 + 2) = k23;
}

// One block per batch: exact top-1000 (desc by key) via MSB radix select + bitonic sort.
// Early-exit: once the selected digit's bin holds exactly 1 key, that key IS the kth;
// one find-scan retrieves it and the remaining passes are skipped.
__global__ __launch_bounds__(1024) void topk_kernel(
    const unsigned long long* __restrict__ keys, unsigned long long* __restrict__ topkeys)
{
  int n = blockIdx.x;
  int tid = threadIdx.x;
  int wave = tid >> 6;
  int lane = tid & 63;
  __shared__ unsigned histW[16 * 257];
  __shared__ unsigned hist[256];
  __shared__ unsigned s_digit, s_Knext, s_cbin, s_cnt;
  __shared__ unsigned long long s_kthkey;
  const unsigned long long* bk = keys + (size_t)n * P_TOT;

  unsigned long long pfx = 0ULL;
  unsigned K = PRE_K;
  bool have_kth = false;
  unsigned long long kth = 0ULL;
  for (int pass = 0; pass < 8; ++pass) {
    int shift = 56 - 8 * pass;
    unsigned long long mask = (pass == 0) ? 0ULL : (~0ULL << (64 - 8 * pass));
    for (int d = tid; d < 16 * 257; d += 1024) histW[d] = 0;
    __syncthreads();
    for (int p = tid; p < P_TOT; p += 1024) {
      unsigned long long k = bk[p];
      if ((k & mask) == pfx)
        atomicAdd(&histW[wave * 257 + ((unsigned)(k >> shift) & 255u)], 1u);
    }
    __syncthreads();
    if (tid < 256) {
      unsigned s = 0;
      for (int w2 = 0; w2 < 16; ++w2) s += histW[w2 * 257 + tid];
      hist[tid] = s;
    }
    __syncthreads();
    // suffix inclusive sum: hist[d] = sum_{d'>=d}
    for (int ofs = 1; ofs < 256; ofs <<= 1) {
      unsigned v = 0;
      if (tid < 256) { v = hist[tid]; if (tid + ofs < 256) v += hist[tid + ofs]; }
      __syncthreads();
      if (tid < 256) hist[tid] = v;
      __syncthreads();
    }
    if (tid < 256) {
      unsigned S = hist[tid];
      unsigned Snext = (tid < 255) ? hist[tid + 1] : 0u;
      if (S >= K && Snext < K) { s_digit = (unsigned)tid; s_Knext = K - Snext; s_cbin = S - Snext; }
    }
    __syncthreads();
    pfx |= ((unsigned long long)s_digit << shift);
    K = s_Knext;
    bool uniq = (s_cbin == 1u);
    __syncthreads();
    if (uniq) {
      if (pass == 7) { have_kth = true; kth = pfx; break; }
      unsigned long long m2 = ~0ULL << (56 - 8 * pass);  // full prefix incl. this digit
      for (int p = tid; p < P_TOT; p += 1024) {
        unsigned long long k = bk[p];
        if ((k & m2) == pfx) s_kthkey = k;
      }
      __syncthreads();
      kth = s_kthkey;
      have_kth = true;
      break;
    }
  }
  if (!have_kth) kth = pfx;

  __shared__ unsigned long long skey[1024];
  skey[tid] = 0ULL;
  if (tid == 0) s_cnt = 0;
  __syncthreads();
  for (int p = tid; p < P_TOT; p += 1024) {
    unsigned long long k = bk[p];
    bool take = (k >= kth);
    unsigned long long b = __ballot(take);
    if (b) {
      int leader = __ffsll((unsigned long long)b) - 1;
      unsigned base = 0;
      if (lane == leader) base = atomicAdd(&s_cnt, (unsigned)__popcll(b));
      base = (unsigned)__shfl((int)base, leader);
      if (take) {
        unsigned pos = base + (unsigned)__popcll(b & ((1ull << lane) - 1ull));
        if (pos < 1024) skey[pos] = k;
      }
    }
  }
  __syncthreads();
  // bitonic sort, descending
  for (int k2 = 2; k2 <= 1024; k2 <<= 1) {
    for (int j = k2 >> 1; j > 0; j >>= 1) {
      int ixj = tid ^ j;
      if (ixj > tid) {
        unsigned long long a = skey[tid], b = skey[ixj];
        bool sw = ((tid & k2) == 0) ? (a < b) : (a > b);
        if (sw) { skey[tid] = b; skey[ixj] = a; }
      }
      __syncthreads();
    }
  }
  topkeys[(size_t)n * 1024 + tid] = skey[tid];
}

__global__ __launch_bounds__(256) void gather_kernel(
    const unsigned long long* __restrict__ topkeys,
    const float* __restrict__ boxes, const int* __restrict__ labels,
    float* __restrict__ tboxes, float* __restrict__ tscores, int* __restrict__ tlabels)
{
  int i = blockIdx.x * 256 + threadIdx.x;
  if (i >= NB * PRE_K) return;
  int n = i / PRE_K;
  int r = i - n * PRE_K;
  unsigned long long k = topkeys[(size_t)n * 1024 + r];
  unsigned idx = 0xFFFFFFFFu - (unsigned)(k & 0xFFFFFFFFu);
  float sc = __uint_as_float((unsigned)(k >> 32));
  size_t src = (size_t)n * P_TOT + idx;
  tscores[i] = sc;
  tlabels[i] = labels[src];
  tboxes[4*(size_t)i+0] = boxes[4*src+0];
  tboxes[4*(size_t)i+1] = boxes[4*src+1];
  tboxes[4*(size_t)i+2] = boxes[4*src+2];
  tboxes[4*(size_t)i+3] = boxes[4*src+3];
}

// COLUMN-major suppression, throughput-shaped.
// grid = (8 j-tiles, 16 i-words, NB).  Thread (jb*128+tid) computes the 64-bit
// word w of column j: bit b set iff i=w*64+b < j and IoU(offset boxes) > 0.6.
// No label test needed: the +label*4096 offset guarantees different-label pairs
// have zero intersection (coords < 4096/2).
__global__ __launch_bounds__(128) void iou_kernel(
    const float* __restrict__ tboxes, const int* __restrict__ tlabels,
    unsigned long long* __restrict__ colsupp)
{
  int jb = blockIdx.x, w = blockIdx.y, n = blockIdx.z;
  int tid = threadIdx.x;
  int j = jb * 128 + tid;
  bool jvalid = (j < PRE_K);

  if (w * 64 >= jb * 128 + 128) {
    if (jvalid) colsupp[((size_t)n * PRE_K + j) * 16 + w] = 0ULL;
    return;
  }

  __shared__ float4 sb[64];
  if (tid < 64) {
    int i = w * 64 + tid;
    float4 v = make_float4(0.f, 0.f, 0.f, 0.f);
    if (i < PRE_K) {
      const float* b = tboxes + ((size_t)n * PRE_K + i) * 4;
      float offv = (float)tlabels[(size_t)n * PRE_K + i] * 4096.0f;
      v = make_float4(b[0] + offv, b[1] + offv, b[2] + offv, b[3] + offv);
    }
    sb[tid] = v;
  }
  __syncthreads();

  float4 bj = make_float4(0.f, 0.f, 0.f, 0.f);
  if (jvalid) {
    const float* b = tboxes + ((size_t)n * PRE_K + j) * 4;
    float offv = (float)tlabels[(size_t)n * PRE_K + j] * 4096.0f;
    bj = make_float4(b[0] + offv, b[1] + offv, b[2] + offv, b[3] + offv);
  }
  float aj = (bj.z - bj.x) * (bj.w - bj.y);

  unsigned long long m = 0;
  int ibase = w * 64;
  #pragma unroll
  for (int b = 0; b < 64; ++b) {
    float4 bi = sb[b];
    float ai = (bi.z - bi.x) * (bi.w - bi.y);
    float lx = fmaxf(bi.x, bj.x), ly = fmaxf(bi.y, bj.y);
    float rx = fminf(bi.z, bj.z), ry = fminf(bi.w, bj.w);
    float iw = fmaxf(rx - lx, 0.f), ih = fmaxf(ry - ly, 0.f);
    float inter = iw * ih;
    float iou = inter / (ai + aj - inter + 1e-9f);
    if (iou > 0.6f && (ibase + b) < j) m |= (1ull << b);
  }
  if (jvalid) colsupp[((size_t)n * PRE_K + j) * 16 + w] = m;
}

// One wave per batch. Fixpoint greedy: per 64-chunk, K = candidates; repeat
// { S = K \ suppressed_by(K); kept |= S; K \= suppressed_by(kept) } until S=0.
// Provably equals the sequential greedy scan (cols only contain rows i<j).
// Cross-chunk words loaded per chunk (future words only), applied post-kept.
__global__ __launch_bounds__(64, 1) void greedy_kernel(
    const unsigned long long* __restrict__ colsupp, const float* __restrict__ tscores,
    unsigned long long* __restrict__ keepmask)
{
  int n = blockIdx.x;
  int l = threadIdx.x;
  const unsigned long long* C = colsupp + (size_t)n * PRE_K * 16;
  const float* sc = tscores + (size_t)n * PRE_K;

  // prefetch all diagonal words + scores (static-indexed -> registers)
  unsigned long long diag[16];
  float sval[16];
  #pragma unroll
  for (int k = 0; k < 16; ++k) {
    int j = k * 64 + l;
    diag[k] = (j < PRE_K) ? C[(size_t)j * 16 + k] : 0ULL;
    sval[k] = (j < PRE_K) ? sc[j] : 0.f;
  }

  unsigned removedbits = 0;  // bit k: column k*64+l removed
  #pragma unroll
  for (int c = 0; c < 16; ++c) {
    // issue future-chunk cross words early; consumed after the fixpoint
    unsigned long long X[16];
    #pragma unroll
    for (int w = 0; w < 16; ++w) {
      X[w] = 0ULL;
      if (w > c) {
        int j = w * 64 + l;
        if (j < PRE_K) X[w] = C[(size_t)j * 16 + c];
      }
    }
    unsigned long long sp = __ballot(sval[c] > 0.f);
    unsigned long long inc = __ballot(((removedbits >> c) & 1u) != 0u);
    unsigned long long K = sp & ~inc;
    unsigned long long col = diag[c];
    unsigned long long kept = 0;
    for (int it = 0; it < 64; ++it) {
      unsigned long long Bsupp = __ballot((col & K) != 0ULL);
      unsigned long long Snew = K & ~Bsupp & ~kept;
      if (Snew == 0ULL) break;
      kept |= Snew;
      unsigned long long Bd = __ballot((col & kept) != 0ULL);
      K &= ~Bd;
    }
    if ((col & kept) != 0ULL) removedbits |= (1u << c);
    #pragma unroll
    for (int w = 0; w < 16; ++w)
      if (w > c && (X[w] & kept) != 0ULL) removedbits |= (1u << w);
  }
  #pragma unroll
  for (int k = 0; k < 16; ++k) {
    unsigned long long w = __ballot(((removedbits >> k) & 1u) != 0u);
    if (l == 0) keepmask[(size_t)n * 16 + k] = w;
  }
}

__global__ __launch_bounds__(1024) void finalize_kernel(
    const unsigned long long* __restrict__ keepmask, const float* __restrict__ tscores,
    const float* __restrict__ tboxes, const int* __restrict__ tlabels,
    float* __restrict__ out)
{
  int n = blockIdx.x;
  int tid = threadIdx.x;
  __shared__ unsigned sk[1024];
  __shared__ unsigned sz[1024];
  bool inr = (tid < PRE_K);
  bool keep = false; float sc = 0.f;
  if (inr) {
    unsigned long long w = keepmask[(size_t)n * 16 + (tid >> 6)];
    bool rem = (w >> (tid & 63)) & 1ull;
    sc = tscores[(size_t)n * PRE_K + tid];
    keep = (!rem) && (sc > 0.f);
  }
  sk[tid] = keep ? 1u : 0u;
  sz[tid] = (inr && !keep) ? 1u : 0u;
  __syncthreads();
  for (int ofs = 1; ofs < 1024; ofs <<= 1) {
    unsigned a = (tid >= ofs) ? sk[tid - ofs] : 0;
    unsigned b = (tid >= ofs) ? sz[tid - ofs] : 0;
    __syncthreads();
    sk[tid] += a; sz[tid] += b;
    __syncthreads();
  }
  int nk = (int)sk[1023];
  int slot = -1;
  if (inr) {
    if (keep) {
      int r = (int)sk[tid] - 1;
      if (r < POST_K) slot = r;
    } else {
      int r = nk + (int)sz[tid] - 1;
      if (r < POST_K) slot = r;
    }
  }
  if (slot >= 0) {
    size_t src = (size_t)n * PRE_K + tid;
    size_t ob = ((size_t)n * POST_K + slot) * 4;
    out[ob+0] = tboxes[4*src+0];
    out[ob+1] = tboxes[4*src+1];
    out[ob+2] = tboxes[4*src+2];
    out[ob+3] = tboxes[4*src+3];
    out[(size_t)NB*POST_K*4 + (size_t)n*POST_K + slot] = keep ? sc : 0.0f;
    out[(size_t)NB*POST_K*5 + (size_t)n*POST_K + slot] = (float)tlabels[src];
  }
}

extern "C" void kernel_launch(void* const* d_in, const int* in_sizes, int n_in,
                              void* d_out, int out_size, void* d_ws, size_t ws_size,
                              hipStream_t stream) {
  char* w = (char*)d_ws;
  auto carve = [&](size_t bytes) { char* p = w; w += (bytes + 255) & ~(size_t)255; return p; };
  float* scores = (float*)carve((size_t)NB * P_TOT * 4);
  int* labels   = (int*)carve((size_t)NB * P_TOT * 4);
  float* boxes  = (float*)carve((size_t)NB * P_TOT * 16);
  unsigned long long* keys    = (unsigned long long*)carve((size_t)NB * P_TOT * 8);
  unsigned long long* topkeys = (unsigned long long*)carve((size_t)NB * 1024 * 8);
  float* tboxes  = (float*)carve((size_t)NB * PRE_K * 16);
  float* tscores = (float*)carve((size_t)NB * PRE_K * 4);
  int* tlabels   = (int*)carve((size_t)NB * PRE_K * 4);
  unsigned long long* colsupp  = (unsigned long long*)carve((size_t)NB * PRE_K * 16 * 8);
  unsigned long long* keepmask = (unsigned long long*)carve((size_t)NB * 16 * 8);

  const float* cls0 = (const float*)d_in[0];
  const float* reg0 = (const float*)d_in[1];
  const float* ctr0 = (const float*)d_in[2];
  const float* cls1 = (const float*)d_in[3];
  const float* reg1 = (const float*)d_in[4];
  const float* ctr1 = (const float*)d_in[5];
  const float* cls2 = (const float*)d_in[6];
  const float* reg2 = (const float*)d_in[7];
  const float* ctr2 = (const float*)d_in[8];
  const float* cls3 = (const float*)d_in[9];
  const float* reg3 = (const float*)d_in[10];
  const float* ctr3 = (const float*)d_in[11];
  const float* cls4 = (const float*)d_in[12];
  const float* reg4 = (const float*)d_in[13];
  const float* ctr4 = (const float*)d_in[14];

  dim3 dg((P4 + 63) / 64, NB);
  decode_kernel<<<dg, 256, 0, stream>>>(cls0, reg0, ctr0, cls1, reg1, ctr1,
                                        cls2, reg2, ctr2, cls3, reg3, ctr3,
                                        cls4, reg4, ctr4,
                                        scores, labels, boxes, keys);
  topk_kernel<<<NB, 1024, 0, stream>>>(keys, topkeys);
  gather_kernel<<<(NB * PRE_K + 255) / 256, 256, 0, stream>>>(topkeys, boxes, labels,
                                                              tboxes, tscores, tlabels);
  dim3 gi(8, 16, NB);
  iou_kernel<<<gi, 128, 0, stream>>>(tboxes, tlabels, colsupp);
  greedy_kernel<<<NB, 64, 0, stream>>>(colsupp, tscores, keepmask);
  finalize_kernel<<<NB, 1024, 0, stream>>>(keepmask, tscores, tboxes, tlabels, (float*)d_out);
}